// Round 1
// baseline (4696.848 us; speedup 1.0000x reference)
//
#include <hip/hip_runtime.h>
#include <hip/hip_bf16.h>
#include <math.h>

// Problem constants
#define SDIM 512
#define BATCH 64
#define LSEQ 512
#define NHEAD 4
#define HDIM 128
#define NAA 20
#define NROWS (BATCH * LSEQ)   // 32768

// ---------------------------------------------------------------------------
// Fused LayerNorm (+ optional affine) (+ optional profile softmax & entropy)
// One block (256 threads) per row of 512.
// ---------------------------------------------------------------------------
template<bool AFFINE, bool PROFILE>
__global__ __launch_bounds__(256) void ln_kernel(
    const float* __restrict__ in, float* __restrict__ out,
    const float* __restrict__ gamma, const float* __restrict__ beta,
    const float* __restrict__ wp, const float* __restrict__ bp,
    float* __restrict__ pe, float* __restrict__ probs)
{
    const int r = blockIdx.x;
    const int t = threadIdx.x;
    const int wave = t >> 6, lane = t & 63;
    const float* row = in + (size_t)r * SDIM;

    float2 v = *(const float2*)(row + t * 2);
    float sum = v.x + v.y;
    float sq  = v.x * v.x + v.y * v.y;
    #pragma unroll
    for (int o = 32; o > 0; o >>= 1) {
        sum += __shfl_down(sum, o);
        sq  += __shfl_down(sq, o);
    }
    __shared__ float red[8];
    __shared__ float mb[2];
    if (lane == 0) { red[wave] = sum; red[4 + wave] = sq; }
    __syncthreads();
    if (t == 0) {
        float s_ = red[0] + red[1] + red[2] + red[3];
        float q_ = red[4] + red[5] + red[6] + red[7];
        float mean = s_ * (1.0f / SDIM);
        float var  = q_ * (1.0f / SDIM) - mean * mean;
        mb[0] = mean;
        mb[1] = rsqrtf(var + 1e-5f);
    }
    __syncthreads();
    const float mean = mb[0], inv = mb[1];
    const float y0 = (v.x - mean) * inv;
    const float y1 = (v.y - mean) * inv;
    float o0 = y0, o1 = y1;
    if (AFFINE) {
        o0 = y0 * gamma[t * 2]     + beta[t * 2];
        o1 = y1 * gamma[t * 2 + 1] + beta[t * 2 + 1];
    }
    *(float2*)(out + (size_t)r * SDIM + t * 2) = make_float2(o0, o1);

    if (PROFILE) {
        float acc[NAA];
        const float* wp0 = wp + (t * 2) * NAA;
        const float* wp1 = wp + (t * 2 + 1) * NAA;
        #pragma unroll
        for (int j = 0; j < NAA; j++) acc[j] = y0 * wp0[j] + y1 * wp1[j];
        #pragma unroll
        for (int j = 0; j < NAA; j++)
            #pragma unroll
            for (int o = 32; o > 0; o >>= 1) acc[j] += __shfl_down(acc[j], o);
        __shared__ float pr[4][NAA];
        __shared__ float lg[NAA];
        if (lane == 0) {
            #pragma unroll
            for (int j = 0; j < NAA; j++) pr[wave][j] = acc[j];
        }
        __syncthreads();
        if (t < NAA) lg[t] = pr[0][t] + pr[1][t] + pr[2][t] + pr[3][t] + bp[t];
        __syncthreads();
        if (t == 0) {
            float mx = lg[0];
            for (int j = 1; j < NAA; j++) mx = fmaxf(mx, lg[j]);
            float e[NAA]; float ssum = 0.f;
            for (int j = 0; j < NAA; j++) { e[j] = expf(lg[j] - mx); ssum += e[j]; }
            float isum = 1.f / ssum, ent = 0.f;
            for (int j = 0; j < NAA; j++) {
                float p = e[j] * isum;
                probs[(size_t)r * NAA + j] = p;
                ent -= p * logf(p + 1e-8f);
            }
            pe[r] = ent;
        }
    }
}

// total_bias[m] = -pe[0,m]*ew + pos_bias[m]   (batch-0 entropy, per reference)
__global__ void bias_kernel(const float* __restrict__ pe,
                            const float* __restrict__ ew,
                            const float* __restrict__ pos,
                            float* __restrict__ tb)
{
    int t = threadIdx.x;  // 512 threads
    tb[t] = -pe[t] * ew[0] + pos[t];
}

// ---------------------------------------------------------------------------
// Generic fp32 tiled GEMM: C[M,N] = A[M,K] @ B[K,N] (+bias)(+relu)(+R)(+=C)
// 64x64 tile, BK=16, 256 threads, 4x4 per thread.
// ---------------------------------------------------------------------------
template<bool BIAS, bool RELU, bool RESID, bool ACCUM>
__global__ __launch_bounds__(256) void gemm64(
    const float* __restrict__ A, int lda,
    const float* __restrict__ B, int ldb,
    float* __restrict__ C, int ldc,
    const float* __restrict__ bias,
    const float* __restrict__ R, int ldr,
    int K)
{
    __shared__ __align__(16) float As[16][68];  // transposed, padded
    __shared__ __align__(16) float Bs[16][64];

    const int m0 = blockIdx.y * 64;
    const int n0 = blockIdx.x * 64;
    const int t  = threadIdx.x;
    const int tx = t & 15, ty = t >> 4;

    float acc[4][4] = {};

    const int arow = t >> 2, ac4 = (t & 3) * 4;
    const int bkr  = t >> 4, bc4 = (t & 15) * 4;
    const float* Ap = A + (size_t)(m0 + arow) * lda + ac4;
    const float* Bp = B + (size_t)bkr * ldb + n0 + bc4;

    for (int k0 = 0; k0 < K; k0 += 16) {
        float4 va = *(const float4*)(Ap + k0);
        float4 vb = *(const float4*)(Bp + (size_t)k0 * ldb);
        As[ac4 + 0][arow] = va.x;
        As[ac4 + 1][arow] = va.y;
        As[ac4 + 2][arow] = va.z;
        As[ac4 + 3][arow] = va.w;
        *(float4*)&Bs[bkr][bc4] = vb;
        __syncthreads();
        #pragma unroll
        for (int kk = 0; kk < 16; kk++) {
            float4 a4 = *(float4*)&As[kk][ty * 4];
            float4 b4 = *(float4*)&Bs[kk][tx * 4];
            float av[4] = {a4.x, a4.y, a4.z, a4.w};
            float bv[4] = {b4.x, b4.y, b4.z, b4.w};
            #pragma unroll
            for (int i = 0; i < 4; i++)
                #pragma unroll
                for (int j = 0; j < 4; j++) acc[i][j] += av[i] * bv[j];
        }
        __syncthreads();
    }

    #pragma unroll
    for (int i = 0; i < 4; i++) {
        const int row = m0 + ty * 4 + i;
        const int col = n0 + tx * 4;
        float4 v = make_float4(acc[i][0], acc[i][1], acc[i][2], acc[i][3]);
        if (BIAS) {
            float4 bb = *(const float4*)(bias + col);
            v.x += bb.x; v.y += bb.y; v.z += bb.z; v.w += bb.w;
        }
        if (RELU) {
            v.x = fmaxf(v.x, 0.f); v.y = fmaxf(v.y, 0.f);
            v.z = fmaxf(v.z, 0.f); v.w = fmaxf(v.w, 0.f);
        }
        if (RESID) {
            float4 rr = *(const float4*)(R + (size_t)row * ldr + col);
            v.x += rr.x; v.y += rr.y; v.z += rr.z; v.w += rr.w;
        }
        if (ACCUM) {
            float4 cc = *(const float4*)(C + (size_t)row * ldc + col);
            v.x += cc.x; v.y += cc.y; v.z += cc.z; v.w += cc.w;
        }
        *(float4*)(C + (size_t)row * ldc + col) = v;
    }
}

// ---------------------------------------------------------------------------
// Attention: one block per (q-tile of 32, head, batch). Full score rows in LDS.
// ---------------------------------------------------------------------------
__global__ __launch_bounds__(256) void attn_kernel(
    const float* __restrict__ Q, const float* __restrict__ K,
    const float* __restrict__ V, const float* __restrict__ tb,
    float* __restrict__ AO, float* __restrict__ W0)
{
    const int qt = blockIdx.x;   // 0..15
    const int h  = blockIdx.y;   // 0..3
    const int b  = blockIdx.z;   // 0..63
    const int t  = threadIdx.x;
    const int tx = t & 15, ty = t >> 4;
    const int wave = t >> 6, lane = t & 63;

    __shared__ __align__(16) float Qt[128][32];     // [k][row]
    __shared__ __align__(16) float KV[8192];        // Kt [k][m] or Vs [m][d]
    __shared__ __align__(16) float Sc[32][513];     // score rows (pad 1)

    const float* Qg = Q + ((size_t)(b * LSEQ + qt * 32)) * SDIM + h * HDIM;
    #pragma unroll
    for (int it = 0; it < 4; ++it) {
        int idx = t + it * 256;
        int row = idx >> 5;
        int c4  = (idx & 31) * 4;
        float4 v = *(const float4*)(Qg + (size_t)row * SDIM + c4);
        Qt[c4 + 0][row] = v.x; Qt[c4 + 1][row] = v.y;
        Qt[c4 + 2][row] = v.z; Qt[c4 + 3][row] = v.w;
    }

    for (int mt = 0; mt < 8; ++mt) {
        __syncthreads();
        const float* Kg = K + ((size_t)(b * LSEQ + mt * 64)) * SDIM + h * HDIM;
        #pragma unroll
        for (int it = 0; it < 8; ++it) {
            int idx = t + it * 256;
            int row = idx >> 5;
            int c4  = (idx & 31) * 4;
            float4 v = *(const float4*)(Kg + (size_t)row * SDIM + c4);
            KV[(c4 + 0) * 64 + row] = v.x;
            KV[(c4 + 1) * 64 + row] = v.y;
            KV[(c4 + 2) * 64 + row] = v.z;
            KV[(c4 + 3) * 64 + row] = v.w;
        }
        __syncthreads();
        float a0[4] = {0.f, 0.f, 0.f, 0.f};
        float a1[4] = {0.f, 0.f, 0.f, 0.f};
        #pragma unroll 4
        for (int k = 0; k < 128; ++k) {
            float q0 = Qt[k][ty * 2];
            float q1 = Qt[k][ty * 2 + 1];
            float4 kv = *(const float4*)&KV[k * 64 + tx * 4];
            a0[0] += q0 * kv.x; a0[1] += q0 * kv.y; a0[2] += q0 * kv.z; a0[3] += q0 * kv.w;
            a1[0] += q1 * kv.x; a1[1] += q1 * kv.y; a1[2] += q1 * kv.z; a1[3] += q1 * kv.w;
        }
        const float scale = 0.08838834764831845f;  // 1/sqrt(128)
        const int base = mt * 64 + tx * 4;
        #pragma unroll
        for (int j = 0; j < 4; j++) {
            Sc[ty * 2][base + j]     = a0[j] * scale;
            Sc[ty * 2 + 1][base + j] = a1[j] * scale;
        }
    }
    __syncthreads();

    if (qt == 0) {
        Sc[0][t]       += tb[t];
        Sc[0][t + 256] += tb[t + 256];
    }
    __syncthreads();

    for (int rr = 0; rr < 8; ++rr) {
        const int row = wave * 8 + rr;
        float vals[8];
        float mx = -3.0e38f;
        #pragma unroll
        for (int j = 0; j < 8; j++) {
            vals[j] = Sc[row][lane + j * 64];
            mx = fmaxf(mx, vals[j]);
        }
        #pragma unroll
        for (int o = 32; o > 0; o >>= 1) mx = fmaxf(mx, __shfl_xor(mx, o));
        float ssum = 0.f;
        #pragma unroll
        for (int j = 0; j < 8; j++) { vals[j] = expf(vals[j] - mx); ssum += vals[j]; }
        #pragma unroll
        for (int o = 32; o > 0; o >>= 1) ssum += __shfl_xor(ssum, o);
        const float inv = 1.f / ssum;
        float* w0row = W0 + ((size_t)(b * LSEQ + qt * 32 + row)) * LSEQ;
        #pragma unroll
        for (int j = 0; j < 8; j++) {
            float p = vals[j] * inv;
            Sc[row][lane + j * 64] = p;
            if (h == 0) w0row[lane + j * 64] = p;
        }
    }

    float o0[8] = {}, o1[8] = {};
    for (int mt = 0; mt < 8; ++mt) {
        __syncthreads();
        const float* Vg = V + ((size_t)(b * LSEQ + mt * 64)) * SDIM + h * HDIM;
        #pragma unroll
        for (int it = 0; it < 8; ++it) {
            int idx = t + it * 256;
            int row = idx >> 5;
            int c4  = (idx & 31) * 4;
            *(float4*)&KV[row * 128 + c4] = *(const float4*)(Vg + (size_t)row * SDIM + c4);
        }
        __syncthreads();
        #pragma unroll 2
        for (int m = 0; m < 64; ++m) {
            float p0 = Sc[ty * 2][mt * 64 + m];
            float p1 = Sc[ty * 2 + 1][mt * 64 + m];
            float4 va = *(const float4*)&KV[m * 128 + tx * 8];
            float4 vb = *(const float4*)&KV[m * 128 + tx * 8 + 4];
            o0[0] += p0 * va.x; o0[1] += p0 * va.y; o0[2] += p0 * va.z; o0[3] += p0 * va.w;
            o0[4] += p0 * vb.x; o0[5] += p0 * vb.y; o0[6] += p0 * vb.z; o0[7] += p0 * vb.w;
            o1[0] += p1 * va.x; o1[1] += p1 * va.y; o1[2] += p1 * va.z; o1[3] += p1 * va.w;
            o1[4] += p1 * vb.x; o1[5] += p1 * vb.y; o1[6] += p1 * vb.z; o1[7] += p1 * vb.w;
        }
    }
    const int row0 = b * LSEQ + qt * 32 + ty * 2;
    float* d0 = AO + (size_t)row0 * SDIM + h * HDIM + tx * 8;
    float* d1 = AO + (size_t)(row0 + 1) * SDIM + h * HDIM + tx * 8;
    *(float4*)d0       = make_float4(o0[0], o0[1], o0[2], o0[3]);
    *(float4*)(d0 + 4) = make_float4(o0[4], o0[5], o0[6], o0[7]);
    *(float4*)d1       = make_float4(o1[0], o1[1], o1[2], o1[3]);
    *(float4*)(d1 + 4) = make_float4(o1[4], o1[5], o1[6], o1[7]);
}

// out0 = s2 + b2 (broadcast)
__global__ __launch_bounds__(256) void init_out_kernel(
    const float* __restrict__ s2, const float* __restrict__ b2,
    float* __restrict__ out)
{
    size_t i = (size_t)blockIdx.x * 256 + threadIdx.x;  // float4 index
    float4 v = ((const float4*)s2)[i];
    int col = ((int)(i & 127)) * 4;
    float4 bb = *(const float4*)(b2 + col);
    v.x += bb.x; v.y += bb.y; v.z += bb.z; v.w += bb.w;
    ((float4*)out)[i] = v;
}

// ---------------------------------------------------------------------------
extern "C" void kernel_launch(void* const* d_in, const int* in_sizes, int n_in,
                              void* d_out, int out_size, void* d_ws, size_t ws_size,
                              hipStream_t stream)
{
    const float* s   = (const float*)d_in[0];
    const float* z   = (const float*)d_in[1];
    const float* wq  = (const float*)d_in[2];
    const float* bq  = (const float*)d_in[3];
    const float* wk  = (const float*)d_in[4];
    const float* bk  = (const float*)d_in[5];
    const float* wv  = (const float*)d_in[6];
    const float* bv  = (const float*)d_in[7];
    const float* wo  = (const float*)d_in[8];
    const float* bo  = (const float*)d_in[9];
    const float* wp  = (const float*)d_in[10];
    const float* bp  = (const float*)d_in[11];
    const float* pos = (const float*)d_in[12];
    const float* ew  = (const float*)d_in[13];
    const float* lng = (const float*)d_in[14];
    const float* lnb = (const float*)d_in[15];
    const float* w1  = (const float*)d_in[16];
    const float* b1  = (const float*)d_in[17];
    const float* w2  = (const float*)d_in[18];
    const float* b2  = (const float*)d_in[19];

    float* out = (float*)d_out;
    const size_t oz  = (size_t)NROWS * SDIM;       // z           @ 16777216
    const size_t ow  = oz + (size_t)NROWS * 64;    // attn head0  @ 18874368
    const size_t ope = ow + (size_t)NROWS * LSEQ;  // entropy     @ 35651584
    const size_t opr = ope + (size_t)NROWS;        // probs       @ 35684352

    float* ws = (float*)d_ws;
    float* X  = ws;               // s_ln, later attn_out
    float* Qb = ws + 16777216;    // q, later s2
    float* Kb = ws + 33554432;    // k, later h
    float* Vb = ws + 50331648;    // v
    float* F  = ws;               // ffn half intermediate (32768x1024), overlaps X+Qb (dead by then)
    float* tb = ws + 67108864;    // 512 floats

    // 1. LN(s) + profile softmax + entropy
    ln_kernel<false, true><<<NROWS, 256, 0, stream>>>(
        s, X, nullptr, nullptr, wp, bp, out + ope, out + opr);

    // 2. total bias from batch-0 entropy
    bias_kernel<<<1, 512, 0, stream>>>(out + ope, ew, pos, tb);

    // 3. QKV projections
    dim3 g512(8, 512);
    gemm64<true, false, false, false><<<g512, 256, 0, stream>>>(
        X, SDIM, wq, SDIM, Qb, SDIM, bq, nullptr, 0, SDIM);
    gemm64<true, false, false, false><<<g512, 256, 0, stream>>>(
        X, SDIM, wk, SDIM, Kb, SDIM, bk, nullptr, 0, SDIM);
    gemm64<true, false, false, false><<<g512, 256, 0, stream>>>(
        X, SDIM, wv, SDIM, Vb, SDIM, bv, nullptr, 0, SDIM);

    // 4. attention
    attn_kernel<<<dim3(16, NHEAD, BATCH), 256, 0, stream>>>(
        Qb, Kb, Vb, tb, X, out + ow);

    // 5. s2 = s + attn_out @ wo + bo
    gemm64<true, false, true, false><<<g512, 256, 0, stream>>>(
        X, SDIM, wo, SDIM, Qb, SDIM, bo, s, SDIM, SDIM);

    // 6. h = LN(s2)*g + b
    ln_kernel<true, false><<<NROWS, 256, 0, stream>>>(
        Qb, Kb, lng, lnb, nullptr, nullptr, nullptr, nullptr);

    // 7. out0 = s2 + b2
    init_out_kernel<<<16384, 256, 0, stream>>>(Qb, b2, out);

    // 8. FFN in two K-halves
    for (int half = 0; half < 2; ++half) {
        gemm64<true, true, false, false><<<dim3(16, 512), 256, 0, stream>>>(
            Kb, SDIM, w1 + half * 1024, 2048, F, 1024, b1 + half * 1024,
            nullptr, 0, SDIM);
        gemm64<false, false, false, true><<<dim3(8, 512), 256, 0, stream>>>(
            F, 1024, w2 + (size_t)half * 1024 * SDIM, SDIM, out, SDIM,
            nullptr, nullptr, 0, 1024);
    }

    // 9. z passthrough
    hipMemcpyAsync(out + oz, z, (size_t)NROWS * 64 * sizeof(float),
                   hipMemcpyDeviceToDevice, stream);
}

// Round 2
// 2240.493 us; speedup vs baseline: 2.0963x; 2.0963x over previous
//
#include <hip/hip_runtime.h>
#include <hip/hip_bf16.h>
#include <math.h>

// Problem constants
#define SDIM 512
#define BATCH 64
#define LSEQ 512
#define NHEAD 4
#define HDIM 128
#define NAA 20
#define NROWS (BATCH * LSEQ)   // 32768

typedef __attribute__((ext_vector_type(8))) short short8;
typedef __attribute__((ext_vector_type(4))) float f32x4;

__device__ __forceinline__ unsigned short f2bf(float f) {
    unsigned int x = __float_as_uint(f);
    unsigned int r = (x + 0x7fffu + ((x >> 16) & 1u)) >> 16;  // RNE
    return (unsigned short)r;
}

__device__ __forceinline__ void load16_lds(const void* g, void* lds) {
    __builtin_amdgcn_global_load_lds(
        (const __attribute__((address_space(1))) unsigned int*)g,
        (__attribute__((address_space(3))) unsigned int*)lds, 16, 0, 0);
}

// ---------------------------------------------------------------------------
// Weight transpose + bf16 convert: W[K][N] fp32 -> Wt[N][K] bf16
// ---------------------------------------------------------------------------
__global__ __launch_bounds__(256) void wtrans(
    const float* __restrict__ W, unsigned short* __restrict__ Wt, int K, int N)
{
    __shared__ float tile[32][33];
    const int t = threadIdx.x, tx = t & 31, ty = t >> 5;
    const int n0 = blockIdx.x * 32, k0 = blockIdx.y * 32;
    #pragma unroll
    for (int p = 0; p < 4; p++)
        tile[ty + p * 8][tx] = W[(size_t)(k0 + ty + p * 8) * N + n0 + tx];
    __syncthreads();
    #pragma unroll
    for (int p = 0; p < 4; p++)
        Wt[(size_t)(n0 + ty + p * 8) * K + k0 + tx] = f2bf(tile[tx][ty + p * 8]);
}

// ---------------------------------------------------------------------------
// Fused LayerNorm (bf16 out) (+ optional affine) (+ optional profile/entropy)
// ---------------------------------------------------------------------------
template<bool AFFINE, bool PROFILE>
__global__ __launch_bounds__(256) void ln_kernel(
    const float* __restrict__ in, unsigned short* __restrict__ out,
    const float* __restrict__ gamma, const float* __restrict__ beta,
    const float* __restrict__ wp, const float* __restrict__ bp,
    float* __restrict__ pe, float* __restrict__ probs)
{
    const int r = blockIdx.x;
    const int t = threadIdx.x;
    const int wave = t >> 6, lane = t & 63;
    const float* row = in + (size_t)r * SDIM;

    float2 v = *(const float2*)(row + t * 2);
    float sum = v.x + v.y;
    float sq  = v.x * v.x + v.y * v.y;
    #pragma unroll
    for (int o = 32; o > 0; o >>= 1) {
        sum += __shfl_down(sum, o);
        sq  += __shfl_down(sq, o);
    }
    __shared__ float red[8];
    __shared__ float mb[2];
    if (lane == 0) { red[wave] = sum; red[4 + wave] = sq; }
    __syncthreads();
    if (t == 0) {
        float s_ = red[0] + red[1] + red[2] + red[3];
        float q_ = red[4] + red[5] + red[6] + red[7];
        float mean = s_ * (1.0f / SDIM);
        float var  = q_ * (1.0f / SDIM) - mean * mean;
        mb[0] = mean;
        mb[1] = rsqrtf(var + 1e-5f);
    }
    __syncthreads();
    const float mean = mb[0], inv = mb[1];
    const float y0 = (v.x - mean) * inv;
    const float y1 = (v.y - mean) * inv;
    float o0 = y0, o1 = y1;
    if (AFFINE) {
        o0 = y0 * gamma[t * 2]     + beta[t * 2];
        o1 = y1 * gamma[t * 2 + 1] + beta[t * 2 + 1];
    }
    unsigned int pk = (unsigned)f2bf(o0) | ((unsigned)f2bf(o1) << 16);
    *(unsigned int*)(out + (size_t)r * SDIM + t * 2) = pk;

    if (PROFILE) {
        float acc[NAA];
        const float* wp0 = wp + (t * 2) * NAA;
        const float* wp1 = wp + (t * 2 + 1) * NAA;
        #pragma unroll
        for (int j = 0; j < NAA; j++) acc[j] = y0 * wp0[j] + y1 * wp1[j];
        #pragma unroll
        for (int j = 0; j < NAA; j++)
            #pragma unroll
            for (int o = 32; o > 0; o >>= 1) acc[j] += __shfl_down(acc[j], o);
        __shared__ float pr[4][NAA];
        __shared__ float lg[NAA];
        if (lane == 0) {
            #pragma unroll
            for (int j = 0; j < NAA; j++) pr[wave][j] = acc[j];
        }
        __syncthreads();
        if (t < NAA) lg[t] = pr[0][t] + pr[1][t] + pr[2][t] + pr[3][t] + bp[t];
        __syncthreads();
        if (t == 0) {
            float mx = lg[0];
            for (int j = 1; j < NAA; j++) mx = fmaxf(mx, lg[j]);
            float e[NAA]; float ssum = 0.f;
            for (int j = 0; j < NAA; j++) { e[j] = expf(lg[j] - mx); ssum += e[j]; }
            float isum = 1.f / ssum, ent = 0.f;
            for (int j = 0; j < NAA; j++) {
                float p = e[j] * isum;
                probs[(size_t)r * NAA + j] = p;
                ent -= p * logf(p + 1e-8f);
            }
            pe[r] = ent;
        }
    }
}

// total_bias[m] = -pe[0,m]*ew + pos_bias[m]
__global__ void bias_kernel(const float* __restrict__ pe,
                            const float* __restrict__ ew,
                            const float* __restrict__ pos,
                            float* __restrict__ tb)
{
    int t = threadIdx.x;  // 512 threads
    tb[t] = -pe[t] * ew[0] + pos[t];
}

// ---------------------------------------------------------------------------
// bf16 MFMA GEMM: C[M,N] = A[M,K](bf16) @ Bt[N,K](bf16)^T  (+bias)(+relu)(+R)(+=C)
// 128x128 tile, BK=64, 4 waves, 4x4 frags of mfma_f32_16x16x32_bf16.
// LDS staged via global_load_lds(16B) with chunk^=(row&7) XOR swizzle
// applied on the SOURCE address (linear LDS dest) and on fragment reads.
// ---------------------------------------------------------------------------
template<int OMODE, bool BIAS, bool RELU, bool RESID, bool ACCUM>
__global__ __launch_bounds__(256) void mgemm(
    const unsigned short* __restrict__ A, int lda,
    const unsigned short* __restrict__ Bt, int ldb,
    void* __restrict__ Cv, int ldc,
    const float* __restrict__ bias,
    const float* __restrict__ R, int ldr,
    int K)
{
    __shared__ __align__(16) unsigned short As[128 * 64];
    __shared__ __align__(16) unsigned short Bs[128 * 64];

    const int t = threadIdx.x;
    const int w = t >> 6, l = t & 63;
    const int wr = w >> 1, wc = w & 1;
    const int m0 = blockIdx.y * 128, n0 = blockIdx.x * 128;

    f32x4 acc[4][4];
    #pragma unroll
    for (int m = 0; m < 4; m++)
        #pragma unroll
        for (int n = 0; n < 4; n++)
            acc[m][n] = (f32x4){0.f, 0.f, 0.f, 0.f};

    // ---- staging addresses: each wave stages 4x 1KB chunks of A and B.
    // LDS dest is linear (base + lane*16); source column pre-swizzled:
    // chunk_src = (l&7) ^ (row&7), row&7 == l>>3 for 8-row groups.
    const int srow  = l >> 3;
    const int swz16 = ((l & 7) ^ srow) << 4;
    const char* pA[4];
    const char* pB[4];
    unsigned ldsoff[4];
    #pragma unroll
    for (int i = 0; i < 4; i++) {
        const int row = (w * 4 + i) * 8 + srow;
        pA[i] = (const char*)A  + (size_t)(m0 + row) * (lda * 2) + swz16;
        pB[i] = (const char*)Bt + (size_t)(n0 + row) * (ldb * 2) + swz16;
        ldsoff[i] = (unsigned)(w * 4 + i) * 1024;
    }

    // ---- fragment read offsets (swizzled): byte = row*128 + ((kk*64+lg*16)^((row&7)<<4))
    const int lg = l >> 4;   // k-group
    const int lr = l & 15;   // row (A) / col (B) within 16
    int arow[4], brow[4];
    #pragma unroll
    for (int m = 0; m < 4; m++) arow[m] = (wr * 64 + m * 16 + lr) * 128;
    #pragma unroll
    for (int n = 0; n < 4; n++) brow[n] = (wc * 64 + n * 16 + lr) * 128;
    const int rsw   = (lr & 7) << 4;
    const int foff0 = (lg * 16) ^ rsw;
    const int foff1 = (64 + lg * 16) ^ rsw;

    for (int k0 = 0; k0 < K; k0 += 64) {
        const size_t kb = (size_t)k0 * 2;
        #pragma unroll
        for (int i = 0; i < 4; i++) {
            load16_lds(pA[i] + kb, (char*)As + ldsoff[i]);
            load16_lds(pB[i] + kb, (char*)Bs + ldsoff[i]);
        }
        __syncthreads();

        short8 af[4], bf[4];
        #pragma unroll
        for (int m = 0; m < 4; m++) af[m] = *(const short8*)((const char*)As + arow[m] + foff0);
        #pragma unroll
        for (int n = 0; n < 4; n++) bf[n] = *(const short8*)((const char*)Bs + brow[n] + foff0);
        #pragma unroll
        for (int m = 0; m < 4; m++)
            #pragma unroll
            for (int n = 0; n < 4; n++)
                acc[m][n] = __builtin_amdgcn_mfma_f32_16x16x32_bf16(af[m], bf[n], acc[m][n], 0, 0, 0);

        #pragma unroll
        for (int m = 0; m < 4; m++) af[m] = *(const short8*)((const char*)As + arow[m] + foff1);
        #pragma unroll
        for (int n = 0; n < 4; n++) bf[n] = *(const short8*)((const char*)Bs + brow[n] + foff1);
        #pragma unroll
        for (int m = 0; m < 4; m++)
            #pragma unroll
            for (int n = 0; n < 4; n++)
                acc[m][n] = __builtin_amdgcn_mfma_f32_16x16x32_bf16(af[m], bf[n], acc[m][n], 0, 0, 0);

        __syncthreads();
    }

    // ---- epilogue: C/D layout col = lane&15, row = (lane>>4)*4 + reg
    #pragma unroll
    for (int n = 0; n < 4; n++) {
        const int col = n0 + wc * 64 + n * 16 + lr;
        const float bv = BIAS ? bias[col] : 0.0f;
        #pragma unroll
        for (int m = 0; m < 4; m++) {
            const int rb = m0 + wr * 64 + m * 16 + lg * 4;
            #pragma unroll
            for (int j = 0; j < 4; j++) {
                float v = acc[m][n][j] + bv;
                if (RELU) v = fmaxf(v, 0.f);
                const size_t row = (size_t)(rb + j);
                if (RESID) v += R[row * ldr + col];
                if (OMODE == 0) {
                    float* Cp = (float*)Cv;
                    const size_t idx = row * ldc + col;
                    if (ACCUM) v += Cp[idx];
                    Cp[idx] = v;
                } else {
                    ((unsigned short*)Cv)[row * ldc + col] = f2bf(v);
                }
            }
        }
    }
}

// ---------------------------------------------------------------------------
// Attention (fp32): one block per (q-tile of 32, head, batch). bf16 attn_out.
// ---------------------------------------------------------------------------
__global__ __launch_bounds__(256) void attn_kernel(
    const float* __restrict__ Q, const float* __restrict__ K,
    const float* __restrict__ V, const float* __restrict__ tb,
    unsigned short* __restrict__ AOb, float* __restrict__ W0)
{
    const int qt = blockIdx.x;
    const int h  = blockIdx.y;
    const int b  = blockIdx.z;
    const int t  = threadIdx.x;
    const int tx = t & 15, ty = t >> 4;
    const int wave = t >> 6, lane = t & 63;

    __shared__ __align__(16) float Qt[128][32];
    __shared__ __align__(16) float KV[8192];
    __shared__ __align__(16) float Sc[32][513];

    const float* Qg = Q + ((size_t)(b * LSEQ + qt * 32)) * SDIM + h * HDIM;
    #pragma unroll
    for (int it = 0; it < 4; ++it) {
        int idx = t + it * 256;
        int row = idx >> 5;
        int c4  = (idx & 31) * 4;
        float4 v = *(const float4*)(Qg + (size_t)row * SDIM + c4);
        Qt[c4 + 0][row] = v.x; Qt[c4 + 1][row] = v.y;
        Qt[c4 + 2][row] = v.z; Qt[c4 + 3][row] = v.w;
    }

    for (int mt = 0; mt < 8; ++mt) {
        __syncthreads();
        const float* Kg = K + ((size_t)(b * LSEQ + mt * 64)) * SDIM + h * HDIM;
        #pragma unroll
        for (int it = 0; it < 8; ++it) {
            int idx = t + it * 256;
            int row = idx >> 5;
            int c4  = (idx & 31) * 4;
            float4 v = *(const float4*)(Kg + (size_t)row * SDIM + c4);
            KV[(c4 + 0) * 64 + row] = v.x;
            KV[(c4 + 1) * 64 + row] = v.y;
            KV[(c4 + 2) * 64 + row] = v.z;
            KV[(c4 + 3) * 64 + row] = v.w;
        }
        __syncthreads();
        float a0[4] = {0.f, 0.f, 0.f, 0.f};
        float a1[4] = {0.f, 0.f, 0.f, 0.f};
        #pragma unroll 4
        for (int k = 0; k < 128; ++k) {
            float q0 = Qt[k][ty * 2];
            float q1 = Qt[k][ty * 2 + 1];
            float4 kv = *(const float4*)&KV[k * 64 + tx * 4];
            a0[0] += q0 * kv.x; a0[1] += q0 * kv.y; a0[2] += q0 * kv.z; a0[3] += q0 * kv.w;
            a1[0] += q1 * kv.x; a1[1] += q1 * kv.y; a1[2] += q1 * kv.z; a1[3] += q1 * kv.w;
        }
        const float scale = 0.08838834764831845f;
        const int base = mt * 64 + tx * 4;
        #pragma unroll
        for (int j = 0; j < 4; j++) {
            Sc[ty * 2][base + j]     = a0[j] * scale;
            Sc[ty * 2 + 1][base + j] = a1[j] * scale;
        }
    }
    __syncthreads();

    if (qt == 0) {
        Sc[0][t]       += tb[t];
        Sc[0][t + 256] += tb[t + 256];
    }
    __syncthreads();

    for (int rr = 0; rr < 8; ++rr) {
        const int row = wave * 8 + rr;
        float vals[8];
        float mx = -3.0e38f;
        #pragma unroll
        for (int j = 0; j < 8; j++) {
            vals[j] = Sc[row][lane + j * 64];
            mx = fmaxf(mx, vals[j]);
        }
        #pragma unroll
        for (int o = 32; o > 0; o >>= 1) mx = fmaxf(mx, __shfl_xor(mx, o));
        float ssum = 0.f;
        #pragma unroll
        for (int j = 0; j < 8; j++) { vals[j] = expf(vals[j] - mx); ssum += vals[j]; }
        #pragma unroll
        for (int o = 32; o > 0; o >>= 1) ssum += __shfl_xor(ssum, o);
        const float inv = 1.f / ssum;
        float* w0row = W0 + ((size_t)(b * LSEQ + qt * 32 + row)) * LSEQ;
        #pragma unroll
        for (int j = 0; j < 8; j++) {
            float p = vals[j] * inv;
            Sc[row][lane + j * 64] = p;
            if (h == 0) w0row[lane + j * 64] = p;
        }
    }

    float o0[8] = {}, o1[8] = {};
    for (int mt = 0; mt < 8; ++mt) {
        __syncthreads();
        const float* Vg = V + ((size_t)(b * LSEQ + mt * 64)) * SDIM + h * HDIM;
        #pragma unroll
        for (int it = 0; it < 8; ++it) {
            int idx = t + it * 256;
            int row = idx >> 5;
            int c4  = (idx & 31) * 4;
            *(float4*)&KV[row * 128 + c4] = *(const float4*)(Vg + (size_t)row * SDIM + c4);
        }
        __syncthreads();
        #pragma unroll 2
        for (int m = 0; m < 64; ++m) {
            float p0 = Sc[ty * 2][mt * 64 + m];
            float p1 = Sc[ty * 2 + 1][mt * 64 + m];
            float4 va = *(const float4*)&KV[m * 128 + tx * 8];
            float4 vb = *(const float4*)&KV[m * 128 + tx * 8 + 4];
            o0[0] += p0 * va.x; o0[1] += p0 * va.y; o0[2] += p0 * va.z; o0[3] += p0 * va.w;
            o0[4] += p0 * vb.x; o0[5] += p0 * vb.y; o0[6] += p0 * vb.z; o0[7] += p0 * vb.w;
            o1[0] += p1 * va.x; o1[1] += p1 * va.y; o1[2] += p1 * va.z; o1[3] += p1 * va.w;
            o1[4] += p1 * vb.x; o1[5] += p1 * vb.y; o1[6] += p1 * vb.z; o1[7] += p1 * vb.w;
        }
    }
    const int row0 = b * LSEQ + qt * 32 + ty * 2;
    unsigned short* d0 = AOb + (size_t)row0 * SDIM + h * HDIM + tx * 8;
    #pragma unroll
    for (int j = 0; j < 8; j++) {
        d0[j]        = f2bf(o0[j]);
        d0[SDIM + j] = f2bf(o1[j]);
    }
}

// out0 = s2 + b2 (broadcast)
__global__ __launch_bounds__(256) void init_out_kernel(
    const float* __restrict__ s2, const float* __restrict__ b2,
    float* __restrict__ out)
{
    size_t i = (size_t)blockIdx.x * 256 + threadIdx.x;
    float4 v = ((const float4*)s2)[i];
    int col = ((int)(i & 127)) * 4;
    float4 bb = *(const float4*)(b2 + col);
    v.x += bb.x; v.y += bb.y; v.z += bb.z; v.w += bb.w;
    ((float4*)out)[i] = v;
}

// ---------------------------------------------------------------------------
extern "C" void kernel_launch(void* const* d_in, const int* in_sizes, int n_in,
                              void* d_out, int out_size, void* d_ws, size_t ws_size,
                              hipStream_t stream)
{
    const float* s   = (const float*)d_in[0];
    const float* z   = (const float*)d_in[1];
    const float* wq  = (const float*)d_in[2];
    const float* bq  = (const float*)d_in[3];
    const float* wk  = (const float*)d_in[4];
    const float* bk  = (const float*)d_in[5];
    const float* wv  = (const float*)d_in[6];
    const float* bv  = (const float*)d_in[7];
    const float* wo  = (const float*)d_in[8];
    const float* bo  = (const float*)d_in[9];
    const float* wp  = (const float*)d_in[10];
    const float* bp  = (const float*)d_in[11];
    const float* pos = (const float*)d_in[12];
    const float* ew  = (const float*)d_in[13];
    const float* lng = (const float*)d_in[14];
    const float* lnb = (const float*)d_in[15];
    const float* w1  = (const float*)d_in[16];
    const float* b1  = (const float*)d_in[17];
    const float* w2  = (const float*)d_in[18];
    const float* b2  = (const float*)d_in[19];

    float* out = (float*)d_out;
    const size_t oz  = (size_t)NROWS * SDIM;
    const size_t ow  = oz + (size_t)NROWS * 64;
    const size_t ope = ow + (size_t)NROWS * LSEQ;
    const size_t opr = ope + (size_t)NROWS;

    // workspace byte layout
    char* wsb = (char*)d_ws;
    float* Qb = (float*)(wsb);                    // q fp32, later s2 fp32
    float* Kb = (float*)(wsb + 67108864);         // k fp32
    float* Vb = (float*)(wsb + 134217728);        // v fp32
    unsigned short* Xb  = (unsigned short*)(wsb + 201326592); // s_ln bf16, later attn_out bf16
    unsigned short* hb  = (unsigned short*)(wsb + 67108864);  // LN2 out bf16 (overlays Kb)
    unsigned short* F   = (unsigned short*)(wsb + 134217728); // ffn half intermediate bf16 (overlays Vb)
    unsigned short* wqt = (unsigned short*)(wsb + 234881024);
    unsigned short* wkt = wqt + 262144;
    unsigned short* wvt = wkt + 262144;
    unsigned short* wot = wvt + 262144;
    unsigned short* w1t = wot + 262144;           // [2048][512]
    unsigned short* w2t = w1t + 1048576;          // [512][2048]
    float* tb = (float*)(wsb + 241172480);

    // 0. weight transpose + bf16 convert
    wtrans<<<dim3(16, 16), 256, 0, stream>>>(wq, wqt, 512, 512);
    wtrans<<<dim3(16, 16), 256, 0, stream>>>(wk, wkt, 512, 512);
    wtrans<<<dim3(16, 16), 256, 0, stream>>>(wv, wvt, 512, 512);
    wtrans<<<dim3(16, 16), 256, 0, stream>>>(wo, wot, 512, 512);
    wtrans<<<dim3(64, 16), 256, 0, stream>>>(w1, w1t, 512, 2048);
    wtrans<<<dim3(16, 64), 256, 0, stream>>>(w2, w2t, 2048, 512);

    // 1. LN(s) -> bf16 + profile softmax + entropy
    ln_kernel<false, true><<<NROWS, 256, 0, stream>>>(
        s, Xb, nullptr, nullptr, wp, bp, out + ope, out + opr);

    // 2. total bias from batch-0 entropy
    bias_kernel<<<1, 512, 0, stream>>>(out + ope, ew, pos, tb);

    // 3. QKV projections (bf16 MFMA, fp32 out)
    dim3 g512(4, 256);
    mgemm<0, true, false, false, false><<<g512, 256, 0, stream>>>(
        Xb, 512, wqt, 512, Qb, 512, bq, nullptr, 0, 512);
    mgemm<0, true, false, false, false><<<g512, 256, 0, stream>>>(
        Xb, 512, wkt, 512, Kb, 512, bk, nullptr, 0, 512);
    mgemm<0, true, false, false, false><<<g512, 256, 0, stream>>>(
        Xb, 512, wvt, 512, Vb, 512, bv, nullptr, 0, 512);

    // 4. attention -> attn_out bf16 (into Xb region), head-0 weights to d_out
    attn_kernel<<<dim3(16, NHEAD, BATCH), 256, 0, stream>>>(
        Qb, Kb, Vb, tb, Xb, out + ow);

    // 5. s2 = s + attn_out @ wo + bo  (fp32 into Qb)
    mgemm<0, true, false, true, false><<<g512, 256, 0, stream>>>(
        Xb, 512, wot, 512, Qb, 512, bo, s, 512, 512);

    // 6. h = LN(s2)*g + b -> bf16 (into Kb region)
    ln_kernel<true, false><<<NROWS, 256, 0, stream>>>(
        Qb, hb, lng, lnb, nullptr, nullptr, nullptr, nullptr);

    // 7. out0 = s2 + b2
    init_out_kernel<<<16384, 256, 0, stream>>>(Qb, b2, out);

    // 8. FFN in two K-halves: out0 += relu(h @ w1_half + b1_half) @ w2_half
    for (int half = 0; half < 2; ++half) {
        mgemm<1, true, true, false, false><<<dim3(8, 256), 256, 0, stream>>>(
            hb, 512, w1t + (size_t)half * 1024 * 512, 512, F, 1024,
            b1 + half * 1024, nullptr, 0, 512);
        mgemm<0, false, false, false, true><<<dim3(4, 256), 256, 0, stream>>>(
            F, 1024, w2t + half * 1024, 2048, out, 512,
            nullptr, nullptr, 0, 1024);
    }

    // 9. z passthrough
    hipMemcpyAsync(out + oz, z, (size_t)NROWS * 64 * sizeof(float),
                   hipMemcpyDeviceToDevice, stream);
}

// Round 3
// 892.975 us; speedup vs baseline: 5.2598x; 2.5090x over previous
//
#include <hip/hip_runtime.h>
#include <hip/hip_bf16.h>
#include <math.h>

// Problem constants
#define SDIM 512
#define BATCH 64
#define LSEQ 512
#define NHEAD 4
#define HDIM 128
#define NAA 20
#define NROWS (BATCH * LSEQ)   // 32768

typedef __attribute__((ext_vector_type(8))) short short8;
typedef __attribute__((ext_vector_type(4))) float f32x4;

__device__ __forceinline__ unsigned short f2bf(float f) {
    unsigned int x = __float_as_uint(f);
    unsigned int r = (x + 0x7fffu + ((x >> 16) & 1u)) >> 16;  // RNE
    return (unsigned short)r;
}

__device__ __forceinline__ void load16_lds(const void* g, void* lds) {
    __builtin_amdgcn_global_load_lds(
        (const __attribute__((address_space(1))) unsigned int*)g,
        (__attribute__((address_space(3))) unsigned int*)lds, 16, 0, 0);
}

// ---------------------------------------------------------------------------
// Weight transpose + bf16 convert: W[K][N] fp32 -> Wt[N][K] bf16
// ---------------------------------------------------------------------------
__global__ __launch_bounds__(256) void wtrans(
    const float* __restrict__ W, unsigned short* __restrict__ Wt, int K, int N)
{
    __shared__ float tile[32][33];
    const int t = threadIdx.x, tx = t & 31, ty = t >> 5;
    const int n0 = blockIdx.x * 32, k0 = blockIdx.y * 32;
    #pragma unroll
    for (int p = 0; p < 4; p++)
        tile[ty + p * 8][tx] = W[(size_t)(k0 + ty + p * 8) * N + n0 + tx];
    __syncthreads();
    #pragma unroll
    for (int p = 0; p < 4; p++)
        Wt[(size_t)(n0 + ty + p * 8) * K + k0 + tx] = f2bf(tile[tx][ty + p * 8]);
}

// ---------------------------------------------------------------------------
// Fused LayerNorm (bf16 out) (+ optional affine) (+ optional profile/entropy)
// ---------------------------------------------------------------------------
template<bool AFFINE, bool PROFILE>
__global__ __launch_bounds__(256) void ln_kernel(
    const float* __restrict__ in, unsigned short* __restrict__ out,
    const float* __restrict__ gamma, const float* __restrict__ beta,
    const float* __restrict__ wp, const float* __restrict__ bp,
    float* __restrict__ pe, float* __restrict__ probs)
{
    const int r = blockIdx.x;
    const int t = threadIdx.x;
    const int wave = t >> 6, lane = t & 63;
    const float* row = in + (size_t)r * SDIM;

    float2 v = *(const float2*)(row + t * 2);
    float sum = v.x + v.y;
    float sq  = v.x * v.x + v.y * v.y;
    #pragma unroll
    for (int o = 32; o > 0; o >>= 1) {
        sum += __shfl_down(sum, o);
        sq  += __shfl_down(sq, o);
    }
    __shared__ float red[8];
    __shared__ float mb[2];
    if (lane == 0) { red[wave] = sum; red[4 + wave] = sq; }
    __syncthreads();
    if (t == 0) {
        float s_ = red[0] + red[1] + red[2] + red[3];
        float q_ = red[4] + red[5] + red[6] + red[7];
        float mean = s_ * (1.0f / SDIM);
        float var  = q_ * (1.0f / SDIM) - mean * mean;
        mb[0] = mean;
        mb[1] = rsqrtf(var + 1e-5f);
    }
    __syncthreads();
    const float mean = mb[0], inv = mb[1];
    const float y0 = (v.x - mean) * inv;
    const float y1 = (v.y - mean) * inv;
    float o0 = y0, o1 = y1;
    if (AFFINE) {
        o0 = y0 * gamma[t * 2]     + beta[t * 2];
        o1 = y1 * gamma[t * 2 + 1] + beta[t * 2 + 1];
    }
    unsigned int pk = (unsigned)f2bf(o0) | ((unsigned)f2bf(o1) << 16);
    *(unsigned int*)(out + (size_t)r * SDIM + t * 2) = pk;

    if (PROFILE) {
        float acc[NAA];
        const float* wp0 = wp + (t * 2) * NAA;
        const float* wp1 = wp + (t * 2 + 1) * NAA;
        #pragma unroll
        for (int j = 0; j < NAA; j++) acc[j] = y0 * wp0[j] + y1 * wp1[j];
        #pragma unroll
        for (int j = 0; j < NAA; j++)
            #pragma unroll
            for (int o = 32; o > 0; o >>= 1) acc[j] += __shfl_down(acc[j], o);
        __shared__ float pr[4][NAA];
        __shared__ float lg[NAA];
        if (lane == 0) {
            #pragma unroll
            for (int j = 0; j < NAA; j++) pr[wave][j] = acc[j];
        }
        __syncthreads();
        if (t < NAA) lg[t] = pr[0][t] + pr[1][t] + pr[2][t] + pr[3][t] + bp[t];
        __syncthreads();
        if (t == 0) {
            float mx = lg[0];
            for (int j = 1; j < NAA; j++) mx = fmaxf(mx, lg[j]);
            float e[NAA]; float ssum = 0.f;
            for (int j = 0; j < NAA; j++) { e[j] = expf(lg[j] - mx); ssum += e[j]; }
            float isum = 1.f / ssum, ent = 0.f;
            for (int j = 0; j < NAA; j++) {
                float p = e[j] * isum;
                probs[(size_t)r * NAA + j] = p;
                ent -= p * logf(p + 1e-8f);
            }
            pe[r] = ent;
        }
    }
}

// total_bias[m] = -pe[0,m]*ew + pos_bias[m]
__global__ void bias_kernel(const float* __restrict__ pe,
                            const float* __restrict__ ew,
                            const float* __restrict__ pos,
                            float* __restrict__ tb)
{
    int t = threadIdx.x;  // 512 threads
    tb[t] = -pe[t] * ew[0] + pos[t];
}

// ---------------------------------------------------------------------------
// bf16 MFMA GEMM: C[M,N] = A[M,K](bf16) @ Bt[N,K](bf16)^T  (+bias)(+relu)(+R)(+=C)
// ---------------------------------------------------------------------------
template<int OMODE, bool BIAS, bool RELU, bool RESID, bool ACCUM>
__global__ __launch_bounds__(256) void mgemm(
    const unsigned short* __restrict__ A, int lda,
    const unsigned short* __restrict__ Bt, int ldb,
    void* __restrict__ Cv, int ldc,
    const float* __restrict__ bias,
    const float* __restrict__ R, int ldr,
    int K)
{
    __shared__ __align__(16) unsigned short As[128 * 64];
    __shared__ __align__(16) unsigned short Bs[128 * 64];

    const int t = threadIdx.x;
    const int w = t >> 6, l = t & 63;
    const int wr = w >> 1, wc = w & 1;
    const int m0 = blockIdx.y * 128, n0 = blockIdx.x * 128;

    f32x4 acc[4][4];
    #pragma unroll
    for (int m = 0; m < 4; m++)
        #pragma unroll
        for (int n = 0; n < 4; n++)
            acc[m][n] = (f32x4){0.f, 0.f, 0.f, 0.f};

    const int srow  = l >> 3;
    const int swz16 = ((l & 7) ^ srow) << 4;
    const char* pA[4];
    const char* pB[4];
    unsigned ldsoff[4];
    #pragma unroll
    for (int i = 0; i < 4; i++) {
        const int row = (w * 4 + i) * 8 + srow;
        pA[i] = (const char*)A  + (size_t)(m0 + row) * (lda * 2) + swz16;
        pB[i] = (const char*)Bt + (size_t)(n0 + row) * (ldb * 2) + swz16;
        ldsoff[i] = (unsigned)(w * 4 + i) * 1024;
    }

    const int lg = l >> 4;
    const int lr = l & 15;
    int arow[4], brow[4];
    #pragma unroll
    for (int m = 0; m < 4; m++) arow[m] = (wr * 64 + m * 16 + lr) * 128;
    #pragma unroll
    for (int n = 0; n < 4; n++) brow[n] = (wc * 64 + n * 16 + lr) * 128;
    const int rsw   = (lr & 7) << 4;
    const int foff0 = (lg * 16) ^ rsw;
    const int foff1 = (64 + lg * 16) ^ rsw;

    for (int k0 = 0; k0 < K; k0 += 64) {
        const size_t kb = (size_t)k0 * 2;
        #pragma unroll
        for (int i = 0; i < 4; i++) {
            load16_lds(pA[i] + kb, (char*)As + ldsoff[i]);
            load16_lds(pB[i] + kb, (char*)Bs + ldsoff[i]);
        }
        __syncthreads();

        short8 af[4], bf[4];
        #pragma unroll
        for (int m = 0; m < 4; m++) af[m] = *(const short8*)((const char*)As + arow[m] + foff0);
        #pragma unroll
        for (int n = 0; n < 4; n++) bf[n] = *(const short8*)((const char*)Bs + brow[n] + foff0);
        #pragma unroll
        for (int m = 0; m < 4; m++)
            #pragma unroll
            for (int n = 0; n < 4; n++)
                acc[m][n] = __builtin_amdgcn_mfma_f32_16x16x32_bf16(af[m], bf[n], acc[m][n], 0, 0, 0);

        #pragma unroll
        for (int m = 0; m < 4; m++) af[m] = *(const short8*)((const char*)As + arow[m] + foff1);
        #pragma unroll
        for (int n = 0; n < 4; n++) bf[n] = *(const short8*)((const char*)Bs + brow[n] + foff1);
        #pragma unroll
        for (int m = 0; m < 4; m++)
            #pragma unroll
            for (int n = 0; n < 4; n++)
                acc[m][n] = __builtin_amdgcn_mfma_f32_16x16x32_bf16(af[m], bf[n], acc[m][n], 0, 0, 0);

        __syncthreads();
    }

    #pragma unroll
    for (int n = 0; n < 4; n++) {
        const int col = n0 + wc * 64 + n * 16 + lr;
        const float bv = BIAS ? bias[col] : 0.0f;
        #pragma unroll
        for (int m = 0; m < 4; m++) {
            const int rb = m0 + wr * 64 + m * 16 + lg * 4;
            #pragma unroll
            for (int j = 0; j < 4; j++) {
                float v = acc[m][n][j] + bv;
                if (RELU) v = fmaxf(v, 0.f);
                const size_t row = (size_t)(rb + j);
                if (RESID) v += R[row * ldr + col];
                if (OMODE == 0) {
                    float* Cp = (float*)Cv;
                    const size_t idx = row * ldc + col;
                    if (ACCUM) v += Cp[idx];
                    Cp[idx] = v;
                } else {
                    ((unsigned short*)Cv)[row * ldc + col] = f2bf(v);
                }
            }
        }
    }
}

// ---------------------------------------------------------------------------
// MFMA attention. Block: 256 thr (4 waves), each wave owns 32 q-rows.
// Grid (4 qt, 4 h, 64 b). No-max softmax (scores are small by construction):
// single pass, unnormalized P; O and W0 divided by rowsum l at the end.
// ---------------------------------------------------------------------------
__global__ __launch_bounds__(256, 3) void attn_mfma(
    const unsigned short* __restrict__ Qg,  // [32768][512] bf16
    const unsigned short* __restrict__ Kg,
    const unsigned short* __restrict__ Vg,
    const float* __restrict__ tb,           // [512]
    unsigned short* __restrict__ AOb,       // [32768][512] bf16
    float* __restrict__ W0,                 // [64][512][512] (h==0, unnormalized)
    float* __restrict__ lgout)              // [32768] rowsums (h==0)
{
    const int qt = blockIdx.x;   // 0..3
    const int h  = blockIdx.y;   // 0..3
    const int b  = blockIdx.z;   // 0..63
    const int t  = threadIdx.x;
    const int w  = t >> 6, l = t & 63;
    const int lr = l & 15, lg = l >> 4;
    const int qbase = qt * 128 + w * 32;

    __shared__ __align__(16) unsigned short Ks[64 * 128];   // [k][d] swizzled, 16KB
    __shared__ __align__(16) unsigned short Vt[128 * 64];   // [d][k] swizzled, 16KB
    __shared__ __align__(16) unsigned short Pl[4 * 2048];   // per-wave P [32][64], 16KB
    __shared__ float tbs[512];

    // stage bias vector
    tbs[t] = tb[t];
    tbs[t + 256] = tb[t + 256];

    // Q fragments in registers (B-operand): q = qbase + fc*16 + lr, d = ks*32 + lg*8
    short8 qf[2][4];
    #pragma unroll
    for (int fc = 0; fc < 2; fc++) {
        const size_t qrow = (size_t)(b * LSEQ + qbase + fc * 16 + lr) * SDIM + h * HDIM;
        #pragma unroll
        for (int ks = 0; ks < 4; ks++)
            qf[fc][ks] = *(const short8*)(Qg + qrow + ks * 32 + lg * 8);
    }

    f32x4 oacc[2][8];
    #pragma unroll
    for (int m = 0; m < 2; m++)
        #pragma unroll
        for (int n = 0; n < 8; n++)
            oacc[m][n] = (f32x4){0.f, 0.f, 0.f, 0.f};
    float lpart[2] = {0.f, 0.f};

    const float scale = 0.08838834764831845f;  // 1/sqrt(128)
    unsigned short* Plw = Pl + w * 2048;       // this wave's P buffer [32][64]

    for (int kt = 0; kt < 8; ++kt) {
        __syncthreads();   // previous tile fully consumed

        // ---- V loads to regs (pair of k rows, 16 d per thread)
        const int k0 = (l & 31) * 2;
        const int d0 = w * 32 + (l >> 5) * 16;
        const size_t vrow = (size_t)(b * LSEQ + kt * 64 + k0) * SDIM + h * HDIM + d0;
        short8 va0 = *(const short8*)(Vg + vrow);
        short8 va1 = *(const short8*)(Vg + vrow + 8);
        short8 vb0 = *(const short8*)(Vg + vrow + SDIM);
        short8 vb1 = *(const short8*)(Vg + vrow + SDIM + 8);

        // ---- K tile via global_load_lds (source-swizzled, linear LDS dest)
        #pragma unroll
        for (int it = 0; it < 4; it++) {
            const int bi = it * 4 + w;
            const int r  = bi * 4 + lg;
            const int sc = lr ^ (r & 7);
            const char* src = (const char*)Kg +
                (size_t)(b * LSEQ + kt * 64 + r) * (SDIM * 2) + h * 256 + sc * 16;
            load16_lds(src, (char*)Ks + bi * 1024);
        }

        // ---- V transpose into LDS (pair-packed b32 writes, conflict-free)
        #pragma unroll
        for (int j = 0; j < 16; j++) {
            const int d = d0 + j;
            unsigned short lo = (unsigned short)((j < 8) ? va0[j] : va1[j - 8]);
            unsigned short hi = (unsigned short)((j < 8) ? vb0[j] : vb1[j - 8]);
            unsigned int pk = (unsigned)lo | ((unsigned)hi << 16);
            const int addr = d * 128 + ((((k0 >> 3) ^ (d & 7))) << 4) + (k0 & 7) * 2;
            *(unsigned int*)((char*)Vt + addr) = pk;
        }
        __syncthreads();

        // ---- QK^T: S^T[k][q] = mfma(K_frag, Q_frag)
        f32x4 sacc[4][2];
        #pragma unroll
        for (int fm = 0; fm < 4; fm++)
            #pragma unroll
            for (int fc = 0; fc < 2; fc++)
                sacc[fm][fc] = (f32x4){0.f, 0.f, 0.f, 0.f};
        #pragma unroll
        for (int ks = 0; ks < 4; ks++) {
            short8 af[4];
            #pragma unroll
            for (int fm = 0; fm < 4; fm++) {
                const int r2 = fm * 16 + lr;
                af[fm] = *(const short8*)((const char*)Ks +
                          r2 * 256 + (((ks * 4 + lg) ^ (lr & 7)) << 4));
            }
            #pragma unroll
            for (int fm = 0; fm < 4; fm++)
                #pragma unroll
                for (int fc = 0; fc < 2; fc++)
                    sacc[fm][fc] = __builtin_amdgcn_mfma_f32_16x16x32_bf16(
                        af[fm], qf[fc][ks], sacc[fm][fc], 0, 0, 0);
        }

        // ---- exp, rowsum, W0, pack P to LDS
        #pragma unroll
        for (int fm = 0; fm < 4; fm++) {
            #pragma unroll
            for (int fc = 0; fc < 2; fc++) {
                float p0 = sacc[fm][fc][0] * scale;
                float p1 = sacc[fm][fc][1] * scale;
                float p2 = sacc[fm][fc][2] * scale;
                float p3 = sacc[fm][fc][3] * scale;
                if (qt == 0 && w == 0 && fc == 0 && lr == 0) {
                    const int kb = kt * 64 + fm * 16 + lg * 4;
                    p0 += tbs[kb + 0]; p1 += tbs[kb + 1];
                    p2 += tbs[kb + 2]; p3 += tbs[kb + 3];
                }
                p0 = __expf(p0); p1 = __expf(p1);
                p2 = __expf(p2); p3 = __expf(p3);
                lpart[fc] += (p0 + p1) + (p2 + p3);
                if (h == 0) {
                    const int q = qbase + fc * 16 + lr;
                    float* dst = W0 + (size_t)(b * LSEQ + q) * LSEQ +
                                 kt * 64 + fm * 16 + lg * 4;
                    *(float4*)dst = make_float4(p0, p1, p2, p3);
                }
                const int rq = fc * 16 + lr;
                const int chunk = fm * 2 + (lg >> 1);
                const int addr = rq * 128 + ((chunk ^ (rq & 7)) << 4) + (lg & 1) * 8;
                unsigned int lo = (unsigned)f2bf(p0) | ((unsigned)f2bf(p1) << 16);
                unsigned int hi = (unsigned)f2bf(p2) | ((unsigned)f2bf(p3) << 16);
                *(uint2*)((char*)Plw + addr) = make_uint2(lo, hi);
            }
        }

        // ---- PV: O[q][d] += mfma(P_frag, V_frag)
        #pragma unroll
        for (int ks2 = 0; ks2 < 2; ks2++) {
            short8 pf[2];
            #pragma unroll
            for (int fm2 = 0; fm2 < 2; fm2++) {
                const int rq2 = fm2 * 16 + lr;
                pf[fm2] = *(const short8*)((const char*)Plw +
                           rq2 * 128 + (((ks2 * 4 + lg) ^ (rq2 & 7)) << 4));
            }
            #pragma unroll
            for (int fn = 0; fn < 8; fn++) {
                const int d = fn * 16 + lr;
                short8 vf = *(const short8*)((const char*)Vt +
                             d * 128 + (((ks2 * 4 + lg) ^ (d & 7)) << 4));
                #pragma unroll
                for (int fm2 = 0; fm2 < 2; fm2++)
                    oacc[fm2][fn] = __builtin_amdgcn_mfma_f32_16x16x32_bf16(
                        pf[fm2], vf, oacc[fm2][fn], 0, 0, 0);
            }
        }
    }

    // ---- rowsum reduce across lg, distribute via LDS
    float l0 = lpart[0], l1 = lpart[1];
    l0 += __shfl_xor(l0, 16); l0 += __shfl_xor(l0, 32);
    l1 += __shfl_xor(l1, 16); l1 += __shfl_xor(l1, 32);
    float* lw = (float*)Plw;
    if (lg == 0) { lw[lr] = l0; lw[16 + lr] = l1; }
    if (h == 0 && lg == 0) {
        lgout[b * LSEQ + qbase + lr]      = l0;
        lgout[b * LSEQ + qbase + 16 + lr] = l1;
    }
    __builtin_amdgcn_s_waitcnt(0);  // lgkmcnt(0): lw visible within wave

    // ---- O write (normalized, bf16)
    #pragma unroll
    for (int fm2 = 0; fm2 < 2; fm2++) {
        float linv[4];
        #pragma unroll
        for (int j = 0; j < 4; j++)
            linv[j] = 1.0f / lw[fm2 * 16 + lg * 4 + j];
        #pragma unroll
        for (int fn = 0; fn < 8; fn++) {
            const int d = fn * 16 + lr;
            #pragma unroll
            for (int j = 0; j < 4; j++) {
                const int q = qbase + fm2 * 16 + lg * 4 + j;
                AOb[(size_t)(b * LSEQ + q) * SDIM + h * HDIM + d] =
                    f2bf(oacc[fm2][fn][j] * linv[j]);
            }
        }
    }
}

// W0 /= rowsum
__global__ __launch_bounds__(256) void w0norm(
    float* __restrict__ W0, const float* __restrict__ lsum)
{
    const size_t i = (size_t)blockIdx.x * 256 + threadIdx.x;  // float4 index
    const int row = (int)(i >> 7);                            // 128 float4/row
    float4 v = ((const float4*)W0)[i];
    const float inv = 1.0f / lsum[row];
    v.x *= inv; v.y *= inv; v.z *= inv; v.w *= inv;
    ((float4*)W0)[i] = v;
}

// out0 = s2 + b2 (broadcast)
__global__ __launch_bounds__(256) void init_out_kernel(
    const float* __restrict__ s2, const float* __restrict__ b2,
    float* __restrict__ out)
{
    size_t i = (size_t)blockIdx.x * 256 + threadIdx.x;
    float4 v = ((const float4*)s2)[i];
    int col = ((int)(i & 127)) * 4;
    float4 bb = *(const float4*)(b2 + col);
    v.x += bb.x; v.y += bb.y; v.z += bb.z; v.w += bb.w;
    ((float4*)out)[i] = v;
}

// ---------------------------------------------------------------------------
extern "C" void kernel_launch(void* const* d_in, const int* in_sizes, int n_in,
                              void* d_out, int out_size, void* d_ws, size_t ws_size,
                              hipStream_t stream)
{
    const float* s   = (const float*)d_in[0];
    const float* z   = (const float*)d_in[1];
    const float* wq  = (const float*)d_in[2];
    const float* bq  = (const float*)d_in[3];
    const float* wk  = (const float*)d_in[4];
    const float* bk  = (const float*)d_in[5];
    const float* wv  = (const float*)d_in[6];
    const float* bv  = (const float*)d_in[7];
    const float* wo  = (const float*)d_in[8];
    const float* bo  = (const float*)d_in[9];
    const float* wp  = (const float*)d_in[10];
    const float* bp  = (const float*)d_in[11];
    const float* pos = (const float*)d_in[12];
    const float* ew  = (const float*)d_in[13];
    const float* lng = (const float*)d_in[14];
    const float* lnb = (const float*)d_in[15];
    const float* w1  = (const float*)d_in[16];
    const float* b1  = (const float*)d_in[17];
    const float* w2  = (const float*)d_in[18];
    const float* b2  = (const float*)d_in[19];

    float* out = (float*)d_out;
    const size_t oz  = (size_t)NROWS * SDIM;
    const size_t ow  = oz + (size_t)NROWS * 64;
    const size_t ope = ow + (size_t)NROWS * LSEQ;
    const size_t opr = ope + (size_t)NROWS;

    // workspace layout
    char* wsb = (char*)d_ws;
    unsigned short* Qb = (unsigned short*)(wsb);              // q bf16; later s2 fp32 (64MB region)
    unsigned short* Kb = (unsigned short*)(wsb + 67108864);   // k bf16
    unsigned short* Vb = (unsigned short*)(wsb + 134217728);  // v bf16
    float* s2f = (float*)(wsb);                               // s2 fp32 (overlays Qb region)
    unsigned short* Xb  = (unsigned short*)(wsb + 201326592); // s_ln bf16 -> attn_out bf16
    unsigned short* hb  = (unsigned short*)(wsb + 67108864);  // LN2 out bf16 (overlays Kb)
    unsigned short* F   = (unsigned short*)(wsb + 134217728); // ffn intermediate (overlays Vb)
    unsigned short* wqt = (unsigned short*)(wsb + 234881024);
    unsigned short* wkt = wqt + 262144;
    unsigned short* wvt = wkt + 262144;
    unsigned short* wot = wvt + 262144;
    unsigned short* w1t = wot + 262144;           // [2048][512]
    unsigned short* w2t = w1t + 1048576;          // [512][2048]
    float* tb = (float*)(wsb + 241172480);
    float* lg = (float*)(wsb + 241180672);        // 32768 rowsums

    // 0. weight transpose + bf16 convert
    wtrans<<<dim3(16, 16), 256, 0, stream>>>(wq, wqt, 512, 512);
    wtrans<<<dim3(16, 16), 256, 0, stream>>>(wk, wkt, 512, 512);
    wtrans<<<dim3(16, 16), 256, 0, stream>>>(wv, wvt, 512, 512);
    wtrans<<<dim3(16, 16), 256, 0, stream>>>(wo, wot, 512, 512);
    wtrans<<<dim3(64, 16), 256, 0, stream>>>(w1, w1t, 512, 2048);
    wtrans<<<dim3(16, 64), 256, 0, stream>>>(w2, w2t, 2048, 512);

    // 1. LN(s) -> bf16 + profile softmax + entropy
    ln_kernel<false, true><<<NROWS, 256, 0, stream>>>(
        s, Xb, nullptr, nullptr, wp, bp, out + ope, out + opr);

    // 2. total bias from batch-0 entropy
    bias_kernel<<<1, 512, 0, stream>>>(out + ope, ew, pos, tb);

    // 3. QKV projections (bf16 MFMA -> bf16 out)
    dim3 g512(4, 256);
    mgemm<1, true, false, false, false><<<g512, 256, 0, stream>>>(
        Xb, 512, wqt, 512, Qb, 512, bq, nullptr, 0, 512);
    mgemm<1, true, false, false, false><<<g512, 256, 0, stream>>>(
        Xb, 512, wkt, 512, Kb, 512, bk, nullptr, 0, 512);
    mgemm<1, true, false, false, false><<<g512, 256, 0, stream>>>(
        Xb, 512, wvt, 512, Vb, 512, bv, nullptr, 0, 512);

    // 4. MFMA attention -> attn_out bf16 (Xb), unnormalized W0 + rowsums
    attn_mfma<<<dim3(4, NHEAD, BATCH), 256, 0, stream>>>(
        Qb, Kb, Vb, tb, Xb, out + ow, lg);

    // 4b. normalize W0
    w0norm<<<16384, 256, 0, stream>>>(out + ow, lg);

    // 5. s2 = s + attn_out @ wo + bo  (fp32 into s2f)
    mgemm<0, true, false, true, false><<<g512, 256, 0, stream>>>(
        Xb, 512, wot, 512, s2f, 512, bo, s, 512, 512);

    // 6. h = LN(s2)*g + b -> bf16
    ln_kernel<true, false><<<NROWS, 256, 0, stream>>>(
        s2f, hb, lng, lnb, nullptr, nullptr, nullptr, nullptr);

    // 7. out0 = s2 + b2
    init_out_kernel<<<16384, 256, 0, stream>>>(s2f, b2, out);

    // 8. FFN in two K-halves
    for (int half = 0; half < 2; ++half) {
        mgemm<1, true, true, false, false><<<dim3(8, 256), 256, 0, stream>>>(
            hb, 512, w1t + (size_t)half * 1024 * 512, 512, F, 1024,
            b1 + half * 1024, nullptr, 0, 512);
        mgemm<0, false, false, false, true><<<dim3(4, 256), 256, 0, stream>>>(
            F, 1024, w2t + half * 1024, 2048, out, 512,
            nullptr, nullptr, 0, 1024);
    }

    // 9. z passthrough
    hipMemcpyAsync(out + oz, z, (size_t)NROWS * 64 * sizeof(float),
                   hipMemcpyDeviceToDevice, stream);
}

// Round 4
// 627.152 us; speedup vs baseline: 7.4892x; 1.4239x over previous
//
#include <hip/hip_runtime.h>
#include <hip/hip_bf16.h>
#include <math.h>

// Problem constants
#define SDIM 512
#define BATCH 64
#define LSEQ 512
#define NHEAD 4
#define HDIM 128
#define NAA 20
#define NROWS (BATCH * LSEQ)   // 32768
#define LDQKV 1536

typedef __attribute__((ext_vector_type(8))) short short8;
typedef __attribute__((ext_vector_type(4))) float f32x4;

__device__ __forceinline__ unsigned short f2bf(float f) {
    unsigned int x = __float_as_uint(f);
    unsigned int r = (x + 0x7fffu + ((x >> 16) & 1u)) >> 16;  // RNE
    return (unsigned short)r;
}

__device__ __forceinline__ void load16_lds(const void* g, void* lds) {
    __builtin_amdgcn_global_load_lds(
        (const __attribute__((address_space(1))) unsigned int*)g,
        (__attribute__((address_space(3))) unsigned int*)lds, 16, 0, 0);
}

// ---------------------------------------------------------------------------
// Weight transpose + bf16 convert: W[K][N] fp32 -> Wt[N][K] bf16
// ---------------------------------------------------------------------------
__global__ __launch_bounds__(256) void wtrans(
    const float* __restrict__ W, unsigned short* __restrict__ Wt, int K, int N)
{
    __shared__ float tile[32][33];
    const int t = threadIdx.x, tx = t & 31, ty = t >> 5;
    const int n0 = blockIdx.x * 32, k0 = blockIdx.y * 32;
    #pragma unroll
    for (int p = 0; p < 4; p++)
        tile[ty + p * 8][tx] = W[(size_t)(k0 + ty + p * 8) * N + n0 + tx];
    __syncthreads();
    #pragma unroll
    for (int p = 0; p < 4; p++)
        Wt[(size_t)(n0 + ty + p * 8) * K + k0 + tx] = f2bf(tile[tx][ty + p * 8]);
}

// wp [512][20] fp32 -> wpT [32][512] bf16, rows 20..31 zero
__global__ __launch_bounds__(256) void wptrans(
    const float* __restrict__ wp, unsigned short* __restrict__ wpT)
{
    const int g = blockIdx.x * 256 + threadIdx.x;   // 64 blocks -> 16384
    const int k = g & 511, j = g >> 9;
    float v = (j < NAA) ? wp[(size_t)k * NAA + j] : 0.0f;
    wpT[(size_t)j * 512 + k] = f2bf(v);
}

// pack bq|bk|bv into one 1536 vector
__global__ void bpack(const float* __restrict__ bq, const float* __restrict__ bk,
                      const float* __restrict__ bv, float* __restrict__ bqkv)
{
    int t = threadIdx.x;  // 512
    bqkv[t] = bq[t]; bqkv[512 + t] = bk[t]; bqkv[1024 + t] = bv[t];
}

// ---------------------------------------------------------------------------
// LayerNorm (bf16 out), optional affine. One block per row.
// ---------------------------------------------------------------------------
template<bool AFFINE>
__global__ __launch_bounds__(256) void ln_kernel(
    const float* __restrict__ in, unsigned short* __restrict__ out,
    const float* __restrict__ gamma, const float* __restrict__ beta)
{
    const int r = blockIdx.x;
    const int t = threadIdx.x;
    const int wave = t >> 6, lane = t & 63;
    const float* row = in + (size_t)r * SDIM;

    float2 v = *(const float2*)(row + t * 2);
    float sum = v.x + v.y;
    float sq  = v.x * v.x + v.y * v.y;
    #pragma unroll
    for (int o = 32; o > 0; o >>= 1) {
        sum += __shfl_down(sum, o);
        sq  += __shfl_down(sq, o);
    }
    __shared__ float red[8];
    __shared__ float mb[2];
    if (lane == 0) { red[wave] = sum; red[4 + wave] = sq; }
    __syncthreads();
    if (t == 0) {
        float s_ = red[0] + red[1] + red[2] + red[3];
        float q_ = red[4] + red[5] + red[6] + red[7];
        float mean = s_ * (1.0f / SDIM);
        float var  = q_ * (1.0f / SDIM) - mean * mean;
        mb[0] = mean;
        mb[1] = rsqrtf(var + 1e-5f);
    }
    __syncthreads();
    const float mean = mb[0], inv = mb[1];
    float o0 = (v.x - mean) * inv;
    float o1 = (v.y - mean) * inv;
    if (AFFINE) {
        o0 = o0 * gamma[t * 2]     + beta[t * 2];
        o1 = o1 * gamma[t * 2 + 1] + beta[t * 2 + 1];
    }
    unsigned int pk = (unsigned)f2bf(o0) | ((unsigned)f2bf(o1) << 16);
    *(unsigned int*)(out + (size_t)r * SDIM + t * 2) = pk;
}

// ---------------------------------------------------------------------------
// Profile kernel: logits = s_ln(bf16) @ wpT^T + bp, softmax+entropy epilogue.
// M-tile 128, N=32 (20 valid), K=512. 4 waves, wave owns 32 rows (2 m-frags).
// ---------------------------------------------------------------------------
__global__ __launch_bounds__(256) void profile_kernel(
    const unsigned short* __restrict__ A,     // [32768][512] bf16
    const unsigned short* __restrict__ wpT,   // [32][512] bf16 (zero-padded)
    const float* __restrict__ bp,             // [20]
    float* __restrict__ probs,                // [32768][20]
    float* __restrict__ pe)                   // [32768]
{
    __shared__ __align__(16) unsigned short As[128 * 64];

    const int t = threadIdx.x;
    const int w = t >> 6, l = t & 63;
    const int lr = l & 15, lg = l >> 4;
    const int m0 = blockIdx.x * 128;

    f32x4 sacc[2][2];
    #pragma unroll
    for (int m = 0; m < 2; m++)
        #pragma unroll
        for (int n = 0; n < 2; n++)
            sacc[m][n] = (f32x4){0.f, 0.f, 0.f, 0.f};

    const int srow  = l >> 3;
    const int swz16 = ((l & 7) ^ srow) << 4;
    const char* pA[4];
    unsigned ldsoff[4];
    #pragma unroll
    for (int i = 0; i < 4; i++) {
        const int row = (w * 4 + i) * 8 + srow;
        pA[i] = (const char*)A + (size_t)(m0 + row) * 1024 + swz16;
        ldsoff[i] = (unsigned)(w * 4 + i) * 1024;
    }

    const int rsw   = (lr & 7) << 4;
    const int foff0 = (lg * 16) ^ rsw;
    const int foff1 = (64 + lg * 16) ^ rsw;
    int arow[2];
    #pragma unroll
    for (int m = 0; m < 2; m++) arow[m] = (w * 32 + m * 16 + lr) * 128;

    for (int k0 = 0; k0 < 512; k0 += 64) {
        const size_t kb = (size_t)k0 * 2;
        #pragma unroll
        for (int i = 0; i < 4; i++)
            load16_lds(pA[i] + kb, (char*)As + ldsoff[i]);
        __syncthreads();

        short8 af[2], bf[2];
        #pragma unroll
        for (int m = 0; m < 2; m++) af[m] = *(const short8*)((const char*)As + arow[m] + foff0);
        #pragma unroll
        for (int n = 0; n < 2; n++)
            bf[n] = *(const short8*)(wpT + (size_t)(n * 16 + lr) * 512 + k0 + lg * 8);
        #pragma unroll
        for (int m = 0; m < 2; m++)
            #pragma unroll
            for (int n = 0; n < 2; n++)
                sacc[m][n] = __builtin_amdgcn_mfma_f32_16x16x32_bf16(af[m], bf[n], sacc[m][n], 0, 0, 0);

        #pragma unroll
        for (int m = 0; m < 2; m++) af[m] = *(const short8*)((const char*)As + arow[m] + foff1);
        #pragma unroll
        for (int n = 0; n < 2; n++)
            bf[n] = *(const short8*)(wpT + (size_t)(n * 16 + lr) * 512 + k0 + 32 + lg * 8);
        #pragma unroll
        for (int m = 0; m < 2; m++)
            #pragma unroll
            for (int n = 0; n < 2; n++)
                sacc[m][n] = __builtin_amdgcn_mfma_f32_16x16x32_bf16(af[m], bf[n], sacc[m][n], 0, 0, 0);

        __syncthreads();
    }

    // epilogue: softmax + entropy over 20 cols. col = n*16 + lr.
    const float b0 = bp[lr];
    const float b1 = (lr < 4) ? bp[16 + lr] : 0.0f;
    #pragma unroll
    for (int m = 0; m < 2; m++) {
        #pragma unroll
        for (int j = 0; j < 4; j++) {
            const float v0 = sacc[m][0][j] + b0;
            const float e0 = __expf(v0);
            const float v1 = sacc[m][1][j] + b1;
            const float e1 = (lr < 4) ? __expf(v1) : 0.0f;
            float Sp = e0 + e1;
            float Tp = e0 * v0 + ((lr < 4) ? e1 * v1 : 0.0f);
            #pragma unroll
            for (int o = 1; o < 16; o <<= 1) {
                Sp += __shfl_xor(Sp, o);
                Tp += __shfl_xor(Tp, o);
            }
            const float inv = 1.0f / Sp;
            const int row = m0 + w * 32 + m * 16 + lg * 4 + j;
            probs[(size_t)row * NAA + lr] = e0 * inv;
            if (lr < 4) probs[(size_t)row * NAA + 16 + lr] = e1 * inv;
            if (lr == 0) pe[row] = logf(Sp) - Tp * inv;
        }
    }
}

// total_bias[m] = -pe[0,m]*ew + pos_bias[m]
__global__ void bias_kernel(const float* __restrict__ pe,
                            const float* __restrict__ ew,
                            const float* __restrict__ pos,
                            float* __restrict__ tb)
{
    int t = threadIdx.x;  // 512 threads
    tb[t] = -pe[t] * ew[0] + pos[t];
}

// ---------------------------------------------------------------------------
// bf16 MFMA GEMM: C[M,N] = A[M,K](bf16) @ Bt[N,K](bf16)^T  (+bias)(+relu)(+R)
// ---------------------------------------------------------------------------
template<int OMODE, bool BIAS, bool RELU, bool RESID>
__global__ __launch_bounds__(256) void mgemm(
    const unsigned short* __restrict__ A, int lda,
    const unsigned short* __restrict__ Bt, int ldb,
    void* __restrict__ Cv, int ldc,
    const float* __restrict__ bias,
    const float* __restrict__ R, int ldr,
    int K)
{
    __shared__ __align__(16) unsigned short As[128 * 64];
    __shared__ __align__(16) unsigned short Bs[128 * 64];

    const int t = threadIdx.x;
    const int w = t >> 6, l = t & 63;
    const int wr = w >> 1, wc = w & 1;
    const int m0 = blockIdx.y * 128, n0 = blockIdx.x * 128;

    f32x4 acc[4][4];
    #pragma unroll
    for (int m = 0; m < 4; m++)
        #pragma unroll
        for (int n = 0; n < 4; n++)
            acc[m][n] = (f32x4){0.f, 0.f, 0.f, 0.f};

    const int srow  = l >> 3;
    const int swz16 = ((l & 7) ^ srow) << 4;
    const char* pA[4];
    const char* pB[4];
    unsigned ldsoff[4];
    #pragma unroll
    for (int i = 0; i < 4; i++) {
        const int row = (w * 4 + i) * 8 + srow;
        pA[i] = (const char*)A  + (size_t)(m0 + row) * (lda * 2) + swz16;
        pB[i] = (const char*)Bt + (size_t)(n0 + row) * (ldb * 2) + swz16;
        ldsoff[i] = (unsigned)(w * 4 + i) * 1024;
    }

    const int lg = l >> 4;
    const int lr = l & 15;
    int arow[4], brow[4];
    #pragma unroll
    for (int m = 0; m < 4; m++) arow[m] = (wr * 64 + m * 16 + lr) * 128;
    #pragma unroll
    for (int n = 0; n < 4; n++) brow[n] = (wc * 64 + n * 16 + lr) * 128;
    const int rsw   = (lr & 7) << 4;
    const int foff0 = (lg * 16) ^ rsw;
    const int foff1 = (64 + lg * 16) ^ rsw;

    for (int k0 = 0; k0 < K; k0 += 64) {
        const size_t kb = (size_t)k0 * 2;
        #pragma unroll
        for (int i = 0; i < 4; i++) {
            load16_lds(pA[i] + kb, (char*)As + ldsoff[i]);
            load16_lds(pB[i] + kb, (char*)Bs + ldsoff[i]);
        }
        __syncthreads();

        short8 af[4], bf[4];
        #pragma unroll
        for (int m = 0; m < 4; m++) af[m] = *(const short8*)((const char*)As + arow[m] + foff0);
        #pragma unroll
        for (int n = 0; n < 4; n++) bf[n] = *(const short8*)((const char*)Bs + brow[n] + foff0);
        #pragma unroll
        for (int m = 0; m < 4; m++)
            #pragma unroll
            for (int n = 0; n < 4; n++)
                acc[m][n] = __builtin_amdgcn_mfma_f32_16x16x32_bf16(af[m], bf[n], acc[m][n], 0, 0, 0);

        #pragma unroll
        for (int m = 0; m < 4; m++) af[m] = *(const short8*)((const char*)As + arow[m] + foff1);
        #pragma unroll
        for (int n = 0; n < 4; n++) bf[n] = *(const short8*)((const char*)Bs + brow[n] + foff1);
        #pragma unroll
        for (int m = 0; m < 4; m++)
            #pragma unroll
            for (int n = 0; n < 4; n++)
                acc[m][n] = __builtin_amdgcn_mfma_f32_16x16x32_bf16(af[m], bf[n], acc[m][n], 0, 0, 0);

        __syncthreads();
    }

    #pragma unroll
    for (int n = 0; n < 4; n++) {
        const int col = n0 + wc * 64 + n * 16 + lr;
        const float bv = BIAS ? bias[col] : 0.0f;
        #pragma unroll
        for (int m = 0; m < 4; m++) {
            const int rb = m0 + wr * 64 + m * 16 + lg * 4;
            #pragma unroll
            for (int j = 0; j < 4; j++) {
                float v = acc[m][n][j] + bv;
                if (RELU) v = fmaxf(v, 0.f);
                const size_t row = (size_t)(rb + j);
                if (RESID) v += R[row * ldr + col];
                if (OMODE == 0) {
                    ((float*)Cv)[row * ldc + col] = v;
                } else {
                    ((unsigned short*)Cv)[row * ldc + col] = f2bf(v);
                }
            }
        }
    }
}

// ---------------------------------------------------------------------------
// MFMA attention over fused QKV [32768][1536] bf16 (Q|K|V each 512 cols).
// Block: 4 waves, each wave owns 32 q-rows. Grid (4 qt, 4 h, 64 b).
// No-max softmax; unnormalized W0 + rowsums; O normalized in-kernel.
// ---------------------------------------------------------------------------
__global__ __launch_bounds__(256, 3) void attn_mfma(
    const unsigned short* __restrict__ QKV,
    const float* __restrict__ tb,
    unsigned short* __restrict__ AOb,       // [32768][512] bf16
    float* __restrict__ W0,                 // [64][512][512] (h==0, unnormalized)
    float* __restrict__ lgout)              // [32768] rowsums (h==0)
{
    const int qt = blockIdx.x;
    const int h  = blockIdx.y;
    const int b  = blockIdx.z;
    const int t  = threadIdx.x;
    const int w  = t >> 6, l = t & 63;
    const int lr = l & 15, lg = l >> 4;
    const int qbase = qt * 128 + w * 32;

    const unsigned short* Qp = QKV;
    const unsigned short* Kp = QKV + 512;
    const unsigned short* Vp = QKV + 1024;

    __shared__ __align__(16) unsigned short Ks[64 * 128];
    __shared__ __align__(16) unsigned short Vt[128 * 64];
    __shared__ __align__(16) unsigned short Pl[4 * 2048];
    __shared__ float tbs[512];

    tbs[t] = tb[t];
    tbs[t + 256] = tb[t + 256];

    short8 qf[2][4];
    #pragma unroll
    for (int fc = 0; fc < 2; fc++) {
        const size_t qrow = (size_t)(b * LSEQ + qbase + fc * 16 + lr) * LDQKV + h * HDIM;
        #pragma unroll
        for (int ks = 0; ks < 4; ks++)
            qf[fc][ks] = *(const short8*)(Qp + qrow + ks * 32 + lg * 8);
    }

    f32x4 oacc[2][8];
    #pragma unroll
    for (int m = 0; m < 2; m++)
        #pragma unroll
        for (int n = 0; n < 8; n++)
            oacc[m][n] = (f32x4){0.f, 0.f, 0.f, 0.f};
    float lpart[2] = {0.f, 0.f};

    const float scale = 0.08838834764831845f;  // 1/sqrt(128)
    unsigned short* Plw = Pl + w * 2048;

    for (int kt = 0; kt < 8; ++kt) {
        __syncthreads();

        const int k0 = (l & 31) * 2;
        const int d0 = w * 32 + (l >> 5) * 16;
        const size_t vrow = (size_t)(b * LSEQ + kt * 64 + k0) * LDQKV + h * HDIM + d0;
        short8 va0 = *(const short8*)(Vp + vrow);
        short8 va1 = *(const short8*)(Vp + vrow + 8);
        short8 vb0 = *(const short8*)(Vp + vrow + LDQKV);
        short8 vb1 = *(const short8*)(Vp + vrow + LDQKV + 8);

        #pragma unroll
        for (int it = 0; it < 4; it++) {
            const int bi = it * 4 + w;
            const int r  = bi * 4 + lg;
            const int sc = lr ^ (r & 7);
            const char* src = (const char*)Kp +
                (size_t)(b * LSEQ + kt * 64 + r) * (LDQKV * 2) + h * 256 + sc * 16;
            load16_lds(src, (char*)Ks + bi * 1024);
        }

        #pragma unroll
        for (int j = 0; j < 16; j++) {
            const int d = d0 + j;
            unsigned short lo = (unsigned short)((j < 8) ? va0[j] : va1[j - 8]);
            unsigned short hi = (unsigned short)((j < 8) ? vb0[j] : vb1[j - 8]);
            unsigned int pk = (unsigned)lo | ((unsigned)hi << 16);
            const int addr = d * 128 + ((((k0 >> 3) ^ (d & 7))) << 4) + (k0 & 7) * 2;
            *(unsigned int*)((char*)Vt + addr) = pk;
        }
        __syncthreads();

        f32x4 sacc[4][2];
        #pragma unroll
        for (int fm = 0; fm < 4; fm++)
            #pragma unroll
            for (int fc = 0; fc < 2; fc++)
                sacc[fm][fc] = (f32x4){0.f, 0.f, 0.f, 0.f};
        #pragma unroll
        for (int ks = 0; ks < 4; ks++) {
            short8 af[4];
            #pragma unroll
            for (int fm = 0; fm < 4; fm++) {
                const int r2 = fm * 16 + lr;
                af[fm] = *(const short8*)((const char*)Ks +
                          r2 * 256 + (((ks * 4 + lg) ^ (lr & 7)) << 4));
            }
            #pragma unroll
            for (int fm = 0; fm < 4; fm++)
                #pragma unroll
                for (int fc = 0; fc < 2; fc++)
                    sacc[fm][fc] = __builtin_amdgcn_mfma_f32_16x16x32_bf16(
                        af[fm], qf[fc][ks], sacc[fm][fc], 0, 0, 0);
        }

        #pragma unroll
        for (int fm = 0; fm < 4; fm++) {
            #pragma unroll
            for (int fc = 0; fc < 2; fc++) {
                float p0 = sacc[fm][fc][0] * scale;
                float p1 = sacc[fm][fc][1] * scale;
                float p2 = sacc[fm][fc][2] * scale;
                float p3 = sacc[fm][fc][3] * scale;
                if (qt == 0 && w == 0 && fc == 0 && lr == 0) {
                    const int kb = kt * 64 + fm * 16 + lg * 4;
                    p0 += tbs[kb + 0]; p1 += tbs[kb + 1];
                    p2 += tbs[kb + 2]; p3 += tbs[kb + 3];
                }
                p0 = __expf(p0); p1 = __expf(p1);
                p2 = __expf(p2); p3 = __expf(p3);
                lpart[fc] += (p0 + p1) + (p2 + p3);
                if (h == 0) {
                    const int q = qbase + fc * 16 + lr;
                    float* dst = W0 + (size_t)(b * LSEQ + q) * LSEQ +
                                 kt * 64 + fm * 16 + lg * 4;
                    *(float4*)dst = make_float4(p0, p1, p2, p3);
                }
                const int rq = fc * 16 + lr;
                const int chunk = fm * 2 + (lg >> 1);
                const int addr = rq * 128 + ((chunk ^ (rq & 7)) << 4) + (lg & 1) * 8;
                unsigned int lo = (unsigned)f2bf(p0) | ((unsigned)f2bf(p1) << 16);
                unsigned int hi = (unsigned)f2bf(p2) | ((unsigned)f2bf(p3) << 16);
                *(uint2*)((char*)Plw + addr) = make_uint2(lo, hi);
            }
        }

        #pragma unroll
        for (int ks2 = 0; ks2 < 2; ks2++) {
            short8 pf[2];
            #pragma unroll
            for (int fm2 = 0; fm2 < 2; fm2++) {
                const int rq2 = fm2 * 16 + lr;
                pf[fm2] = *(const short8*)((const char*)Plw +
                           rq2 * 128 + (((ks2 * 4 + lg) ^ (rq2 & 7)) << 4));
            }
            #pragma unroll
            for (int fn = 0; fn < 8; fn++) {
                const int d = fn * 16 + lr;
                short8 vf = *(const short8*)((const char*)Vt +
                             d * 128 + (((ks2 * 4 + lg) ^ (d & 7)) << 4));
                #pragma unroll
                for (int fm2 = 0; fm2 < 2; fm2++)
                    oacc[fm2][fn] = __builtin_amdgcn_mfma_f32_16x16x32_bf16(
                        pf[fm2], vf, oacc[fm2][fn], 0, 0, 0);
            }
        }
    }

    float l0 = lpart[0], l1 = lpart[1];
    l0 += __shfl_xor(l0, 16); l0 += __shfl_xor(l0, 32);
    l1 += __shfl_xor(l1, 16); l1 += __shfl_xor(l1, 32);
    float* lw = (float*)Plw;
    if (lg == 0) { lw[lr] = l0; lw[16 + lr] = l1; }
    if (h == 0 && lg == 0) {
        lgout[b * LSEQ + qbase + lr]      = l0;
        lgout[b * LSEQ + qbase + 16 + lr] = l1;
    }
    __builtin_amdgcn_s_waitcnt(0);

    #pragma unroll
    for (int fm2 = 0; fm2 < 2; fm2++) {
        float linv[4];
        #pragma unroll
        for (int j = 0; j < 4; j++)
            linv[j] = 1.0f / lw[fm2 * 16 + lg * 4 + j];
        #pragma unroll
        for (int fn = 0; fn < 8; fn++) {
            const int d = fn * 16 + lr;
            #pragma unroll
            for (int j = 0; j < 4; j++) {
                const int q = qbase + fm2 * 16 + lg * 4 + j;
                AOb[(size_t)(b * LSEQ + q) * SDIM + h * HDIM + d] =
                    f2bf(oacc[fm2][fn][j] * linv[j]);
            }
        }
    }
}

// W0 /= rowsum
__global__ __launch_bounds__(256) void w0norm(
    float* __restrict__ W0, const float* __restrict__ lsum)
{
    const size_t i = (size_t)blockIdx.x * 256 + threadIdx.x;
    const int row = (int)(i >> 7);
    float4 v = ((const float4*)W0)[i];
    const float inv = 1.0f / lsum[row];
    v.x *= inv; v.y *= inv; v.z *= inv; v.w *= inv;
    ((float4*)W0)[i] = v;
}

// ---------------------------------------------------------------------------
extern "C" void kernel_launch(void* const* d_in, const int* in_sizes, int n_in,
                              void* d_out, int out_size, void* d_ws, size_t ws_size,
                              hipStream_t stream)
{
    const float* s   = (const float*)d_in[0];
    const float* z   = (const float*)d_in[1];
    const float* wq  = (const float*)d_in[2];
    const float* bq  = (const float*)d_in[3];
    const float* wk  = (const float*)d_in[4];
    const float* bk  = (const float*)d_in[5];
    const float* wv  = (const float*)d_in[6];
    const float* bv  = (const float*)d_in[7];
    const float* wo  = (const float*)d_in[8];
    const float* bo  = (const float*)d_in[9];
    const float* wp  = (const float*)d_in[10];
    const float* bp  = (const float*)d_in[11];
    const float* pos = (const float*)d_in[12];
    const float* ew  = (const float*)d_in[13];
    const float* lng = (const float*)d_in[14];
    const float* lnb = (const float*)d_in[15];
    const float* w1  = (const float*)d_in[16];
    const float* b1  = (const float*)d_in[17];
    const float* w2  = (const float*)d_in[18];
    const float* b2  = (const float*)d_in[19];

    float* out = (float*)d_out;
    const size_t oz  = (size_t)NROWS * SDIM;
    const size_t ow  = oz + (size_t)NROWS * 64;
    const size_t ope = ow + (size_t)NROWS * LSEQ;
    const size_t opr = ope + (size_t)NROWS;

    // workspace layout (bytes)
    char* wsb = (char*)d_ws;
    unsigned short* QKV = (unsigned short*)(wsb);             // [32768][1536] bf16, 96MB
    float*          s2f = (float*)(wsb);                      // s2 fp32 64MB (after attn)
    unsigned short* hb  = (unsigned short*)(wsb + 67108864);  // LN2 bf16 32MB (after attn)
    unsigned short* Xb  = (unsigned short*)(wsb + 100663296); // s_ln bf16 -> attn_out bf16
    unsigned short* F   = (unsigned short*)(wsb + 100663296); // FFN mid [32768][2048] bf16, 128MB (after WO)
    unsigned short* wqkvt = (unsigned short*)(wsb + 234881024);
    unsigned short* wot = wqkvt + 786432;
    unsigned short* w1t = wqkvt + 1048576;    // [2048][512]
    unsigned short* w2t = wqkvt + 2097152;    // [512][2048]
    unsigned short* wpT = wqkvt + 3145728;    // [32][512]
    float* bqkv = (float*)(wsb + 234881024 + 6324224);
    float* tb   = bqkv + 1536;
    float* lgv  = tb + 512;

    // 0. weight prep
    wtrans<<<dim3(16, 16), 256, 0, stream>>>(wq, wqkvt, 512, 512);
    wtrans<<<dim3(16, 16), 256, 0, stream>>>(wk, wqkvt + 262144, 512, 512);
    wtrans<<<dim3(16, 16), 256, 0, stream>>>(wv, wqkvt + 524288, 512, 512);
    wtrans<<<dim3(16, 16), 256, 0, stream>>>(wo, wot, 512, 512);
    wtrans<<<dim3(64, 16), 256, 0, stream>>>(w1, w1t, 512, 2048);
    wtrans<<<dim3(16, 64), 256, 0, stream>>>(w2, w2t, 2048, 512);
    wptrans<<<64, 256, 0, stream>>>(wp, wpT);
    bpack<<<1, 512, 0, stream>>>(bq, bk, bv, bqkv);

    // 1. LN(s) -> bf16 Xb
    ln_kernel<false><<<NROWS, 256, 0, stream>>>(s, Xb, nullptr, nullptr);

    // 1b. profile softmax + entropy (MFMA)
    profile_kernel<<<256, 256, 0, stream>>>(Xb, wpT, bp, out + opr, out + ope);

    // 2. total bias from batch-0 entropy
    bias_kernel<<<1, 512, 0, stream>>>(out + ope, ew, pos, tb);

    // 3. fused QKV projection -> QKV bf16 [32768][1536]
    mgemm<1, true, false, false><<<dim3(12, 256), 256, 0, stream>>>(
        Xb, 512, wqkvt, 512, QKV, LDQKV, bqkv, nullptr, 0, 512);

    // 4. MFMA attention -> attn_out bf16 (Xb), unnormalized W0 + rowsums
    attn_mfma<<<dim3(4, NHEAD, BATCH), 256, 0, stream>>>(
        QKV, tb, Xb, out + ow, lgv);

    // 4b. normalize W0
    w0norm<<<16384, 256, 0, stream>>>(out + ow, lgv);

    // 5. s2 = s + attn_out @ wo + bo  (fp32 into s2f)
    mgemm<0, true, false, true><<<dim3(4, 256), 256, 0, stream>>>(
        Xb, 512, wot, 512, s2f, 512, bo, s, 512, 512);

    // 6. h = LN(s2)*g + b -> bf16
    ln_kernel<true><<<NROWS, 256, 0, stream>>>(s2f, hb, lng, lnb);

    // 7. FFN1: F = relu(h @ w1 + b1), bf16 [32768][2048]
    mgemm<1, true, true, false><<<dim3(16, 256), 256, 0, stream>>>(
        hb, 512, w1t, 512, F, 2048, b1, nullptr, 0, 512);

    // 8. FFN2: out0 = F @ w2 + b2 + s2
    mgemm<0, true, false, true><<<dim3(4, 256), 256, 0, stream>>>(
        F, 2048, w2t, 2048, out, 512, b2, s2f, 512, 2048);

    // 9. z passthrough
    hipMemcpyAsync(out + oz, z, (size_t)NROWS * 64 * sizeof(float),
                   hipMemcpyDeviceToDevice, stream);
}

// Round 5
// 557.916 us; speedup vs baseline: 8.4186x; 1.1241x over previous
//
#include <hip/hip_runtime.h>
#include <hip/hip_bf16.h>
#include <math.h>

// Problem constants
#define SDIM 512
#define BATCH 64
#define LSEQ 512
#define NHEAD 4
#define HDIM 128
#define NAA 20
#define NROWS (BATCH * LSEQ)   // 32768
#define LDQKV 1536

typedef __attribute__((ext_vector_type(8))) short short8;
typedef __attribute__((ext_vector_type(4))) float f32x4;

__device__ __forceinline__ unsigned short f2bf(float f) {
    unsigned int x = __float_as_uint(f);
    unsigned int r = (x + 0x7fffu + ((x >> 16) & 1u)) >> 16;  // RNE
    return (unsigned short)r;
}

__device__ __forceinline__ void load16_lds(const void* g, void* lds) {
    __builtin_amdgcn_global_load_lds(
        (const __attribute__((address_space(1))) unsigned int*)g,
        (__attribute__((address_space(3))) unsigned int*)lds, 16, 0, 0);
}

// ---------------------------------------------------------------------------
// Weight transpose + bf16 convert: W[K][N] fp32 -> Wt[N][K] bf16
// ---------------------------------------------------------------------------
__global__ __launch_bounds__(256) void wtrans(
    const float* __restrict__ W, unsigned short* __restrict__ Wt, int K, int N)
{
    __shared__ float tile[32][33];
    const int t = threadIdx.x, tx = t & 31, ty = t >> 5;
    const int n0 = blockIdx.x * 32, k0 = blockIdx.y * 32;
    #pragma unroll
    for (int p = 0; p < 4; p++)
        tile[ty + p * 8][tx] = W[(size_t)(k0 + ty + p * 8) * N + n0 + tx];
    __syncthreads();
    #pragma unroll
    for (int p = 0; p < 4; p++)
        Wt[(size_t)(n0 + ty + p * 8) * K + k0 + tx] = f2bf(tile[tx][ty + p * 8]);
}

// wp [512][20] fp32 -> wpT [32][512] bf16, rows 20..31 zero
__global__ __launch_bounds__(256) void wptrans(
    const float* __restrict__ wp, unsigned short* __restrict__ wpT)
{
    const int g = blockIdx.x * 256 + threadIdx.x;   // 64 blocks -> 16384
    const int k = g & 511, j = g >> 9;
    float v = (j < NAA) ? wp[(size_t)k * NAA + j] : 0.0f;
    wpT[(size_t)j * 512 + k] = f2bf(v);
}

// pack bq|bk|bv into one 1536 vector
__global__ void bpack(const float* __restrict__ bq, const float* __restrict__ bk,
                      const float* __restrict__ bv, float* __restrict__ bqkv)
{
    int t = threadIdx.x;  // 512
    bqkv[t] = bq[t]; bqkv[512 + t] = bk[t]; bqkv[1024 + t] = bv[t];
}

// ---------------------------------------------------------------------------
// LayerNorm (bf16 out), optional affine. One block per row.
// ---------------------------------------------------------------------------
template<bool AFFINE>
__global__ __launch_bounds__(256) void ln_kernel(
    const float* __restrict__ in, unsigned short* __restrict__ out,
    const float* __restrict__ gamma, const float* __restrict__ beta)
{
    const int r = blockIdx.x;
    const int t = threadIdx.x;
    const int wave = t >> 6, lane = t & 63;
    const float* row = in + (size_t)r * SDIM;

    float2 v = *(const float2*)(row + t * 2);
    float sum = v.x + v.y;
    float sq  = v.x * v.x + v.y * v.y;
    #pragma unroll
    for (int o = 32; o > 0; o >>= 1) {
        sum += __shfl_down(sum, o);
        sq  += __shfl_down(sq, o);
    }
    __shared__ float red[8];
    __shared__ float mb[2];
    if (lane == 0) { red[wave] = sum; red[4 + wave] = sq; }
    __syncthreads();
    if (t == 0) {
        float s_ = red[0] + red[1] + red[2] + red[3];
        float q_ = red[4] + red[5] + red[6] + red[7];
        float mean = s_ * (1.0f / SDIM);
        float var  = q_ * (1.0f / SDIM) - mean * mean;
        mb[0] = mean;
        mb[1] = rsqrtf(var + 1e-5f);
    }
    __syncthreads();
    const float mean = mb[0], inv = mb[1];
    float o0 = (v.x - mean) * inv;
    float o1 = (v.y - mean) * inv;
    if (AFFINE) {
        o0 = o0 * gamma[t * 2]     + beta[t * 2];
        o1 = o1 * gamma[t * 2 + 1] + beta[t * 2 + 1];
    }
    unsigned int pk = (unsigned)f2bf(o0) | ((unsigned)f2bf(o1) << 16);
    *(unsigned int*)(out + (size_t)r * SDIM + t * 2) = pk;
}

// ---------------------------------------------------------------------------
// Profile kernel: logits = s_ln(bf16) @ wpT^T + bp, softmax+entropy epilogue.
// ---------------------------------------------------------------------------
__global__ __launch_bounds__(256) void profile_kernel(
    const unsigned short* __restrict__ A,     // [32768][512] bf16
    const unsigned short* __restrict__ wpT,   // [32][512] bf16 (zero-padded)
    const float* __restrict__ bp,             // [20]
    float* __restrict__ probs,                // [32768][20]
    float* __restrict__ pe)                   // [32768]
{
    __shared__ __align__(16) unsigned short As[128 * 64];

    const int t = threadIdx.x;
    const int w = t >> 6, l = t & 63;
    const int lr = l & 15, lg = l >> 4;
    const int m0 = blockIdx.x * 128;

    f32x4 sacc[2][2];
    #pragma unroll
    for (int m = 0; m < 2; m++)
        #pragma unroll
        for (int n = 0; n < 2; n++)
            sacc[m][n] = (f32x4){0.f, 0.f, 0.f, 0.f};

    const int srow  = l >> 3;
    const int swz16 = ((l & 7) ^ srow) << 4;
    const char* pA[4];
    unsigned ldsoff[4];
    #pragma unroll
    for (int i = 0; i < 4; i++) {
        const int row = (w * 4 + i) * 8 + srow;
        pA[i] = (const char*)A + (size_t)(m0 + row) * 1024 + swz16;
        ldsoff[i] = (unsigned)(w * 4 + i) * 1024;
    }

    const int rsw   = (lr & 7) << 4;
    const int foff0 = (lg * 16) ^ rsw;
    const int foff1 = (64 + lg * 16) ^ rsw;
    int arow[2];
    #pragma unroll
    for (int m = 0; m < 2; m++) arow[m] = (w * 32 + m * 16 + lr) * 128;

    for (int k0 = 0; k0 < 512; k0 += 64) {
        const size_t kb = (size_t)k0 * 2;
        #pragma unroll
        for (int i = 0; i < 4; i++)
            load16_lds(pA[i] + kb, (char*)As + ldsoff[i]);
        __syncthreads();

        short8 af[2], bf[2];
        #pragma unroll
        for (int m = 0; m < 2; m++) af[m] = *(const short8*)((const char*)As + arow[m] + foff0);
        #pragma unroll
        for (int n = 0; n < 2; n++)
            bf[n] = *(const short8*)(wpT + (size_t)(n * 16 + lr) * 512 + k0 + lg * 8);
        #pragma unroll
        for (int m = 0; m < 2; m++)
            #pragma unroll
            for (int n = 0; n < 2; n++)
                sacc[m][n] = __builtin_amdgcn_mfma_f32_16x16x32_bf16(af[m], bf[n], sacc[m][n], 0, 0, 0);

        #pragma unroll
        for (int m = 0; m < 2; m++) af[m] = *(const short8*)((const char*)As + arow[m] + foff1);
        #pragma unroll
        for (int n = 0; n < 2; n++)
            bf[n] = *(const short8*)(wpT + (size_t)(n * 16 + lr) * 512 + k0 + 32 + lg * 8);
        #pragma unroll
        for (int m = 0; m < 2; m++)
            #pragma unroll
            for (int n = 0; n < 2; n++)
                sacc[m][n] = __builtin_amdgcn_mfma_f32_16x16x32_bf16(af[m], bf[n], sacc[m][n], 0, 0, 0);

        __syncthreads();
    }

    const float b0 = bp[lr];
    const float b1 = (lr < 4) ? bp[16 + lr] : 0.0f;
    #pragma unroll
    for (int m = 0; m < 2; m++) {
        #pragma unroll
        for (int j = 0; j < 4; j++) {
            const float v0 = sacc[m][0][j] + b0;
            const float e0 = __expf(v0);
            const float v1 = sacc[m][1][j] + b1;
            const float e1 = (lr < 4) ? __expf(v1) : 0.0f;
            float Sp = e0 + e1;
            float Tp = e0 * v0 + ((lr < 4) ? e1 * v1 : 0.0f);
            #pragma unroll
            for (int o = 1; o < 16; o <<= 1) {
                Sp += __shfl_xor(Sp, o);
                Tp += __shfl_xor(Tp, o);
            }
            const float inv = 1.0f / Sp;
            const int row = m0 + w * 32 + m * 16 + lg * 4 + j;
            probs[(size_t)row * NAA + lr] = e0 * inv;
            if (lr < 4) probs[(size_t)row * NAA + 16 + lr] = e1 * inv;
            if (lr == 0) pe[row] = logf(Sp) - Tp * inv;
        }
    }
}

// total_bias[m] = -pe[0,m]*ew + pos_bias[m]
__global__ void bias_kernel(const float* __restrict__ pe,
                            const float* __restrict__ ew,
                            const float* __restrict__ pos,
                            float* __restrict__ tb)
{
    int t = threadIdx.x;  // 512 threads
    tb[t] = -pe[t] * ew[0] + pos[t];
}

// ---------------------------------------------------------------------------
// bf16 MFMA GEMM with XCD-chunked block swizzle (all grids % 8 == 0).
// ---------------------------------------------------------------------------
template<int OMODE, bool BIAS, bool RELU, bool RESID>
__global__ __launch_bounds__(256) void mgemm(
    const unsigned short* __restrict__ A, int lda,
    const unsigned short* __restrict__ Bt, int ldb,
    void* __restrict__ Cv, int ldc,
    const float* __restrict__ bias,
    const float* __restrict__ R, int ldr,
    int K)
{
    __shared__ __align__(16) unsigned short As[128 * 64];
    __shared__ __align__(16) unsigned short Bs[128 * 64];

    const int t = threadIdx.x;
    const int w = t >> 6, l = t & 63;
    const int wr = w >> 1, wc = w & 1;

    // XCD swizzle: contiguous logical chunk per XCD
    const int gx   = gridDim.x;
    const int nwg  = gx * gridDim.y;
    const int flat = blockIdx.x + gx * blockIdx.y;
    const int cpx  = nwg >> 3;
    const int logical = (flat & 7) * cpx + (flat >> 3);
    const int m0 = (logical / gx) * 128, n0 = (logical % gx) * 128;

    f32x4 acc[4][4];
    #pragma unroll
    for (int m = 0; m < 4; m++)
        #pragma unroll
        for (int n = 0; n < 4; n++)
            acc[m][n] = (f32x4){0.f, 0.f, 0.f, 0.f};

    const int srow  = l >> 3;
    const int swz16 = ((l & 7) ^ srow) << 4;
    const char* pA[4];
    const char* pB[4];
    unsigned ldsoff[4];
    #pragma unroll
    for (int i = 0; i < 4; i++) {
        const int row = (w * 4 + i) * 8 + srow;
        pA[i] = (const char*)A  + (size_t)(m0 + row) * (lda * 2) + swz16;
        pB[i] = (const char*)Bt + (size_t)(n0 + row) * (ldb * 2) + swz16;
        ldsoff[i] = (unsigned)(w * 4 + i) * 1024;
    }

    const int lg = l >> 4;
    const int lr = l & 15;
    int arow[4], brow[4];
    #pragma unroll
    for (int m = 0; m < 4; m++) arow[m] = (wr * 64 + m * 16 + lr) * 128;
    #pragma unroll
    for (int n = 0; n < 4; n++) brow[n] = (wc * 64 + n * 16 + lr) * 128;
    const int rsw   = (lr & 7) << 4;
    const int foff0 = (lg * 16) ^ rsw;
    const int foff1 = (64 + lg * 16) ^ rsw;

    for (int k0 = 0; k0 < K; k0 += 64) {
        const size_t kb = (size_t)k0 * 2;
        #pragma unroll
        for (int i = 0; i < 4; i++) {
            load16_lds(pA[i] + kb, (char*)As + ldsoff[i]);
            load16_lds(pB[i] + kb, (char*)Bs + ldsoff[i]);
        }
        __syncthreads();

        short8 af[4], bf[4];
        #pragma unroll
        for (int m = 0; m < 4; m++) af[m] = *(const short8*)((const char*)As + arow[m] + foff0);
        #pragma unroll
        for (int n = 0; n < 4; n++) bf[n] = *(const short8*)((const char*)Bs + brow[n] + foff0);
        #pragma unroll
        for (int m = 0; m < 4; m++)
            #pragma unroll
            for (int n = 0; n < 4; n++)
                acc[m][n] = __builtin_amdgcn_mfma_f32_16x16x32_bf16(af[m], bf[n], acc[m][n], 0, 0, 0);

        #pragma unroll
        for (int m = 0; m < 4; m++) af[m] = *(const short8*)((const char*)As + arow[m] + foff1);
        #pragma unroll
        for (int n = 0; n < 4; n++) bf[n] = *(const short8*)((const char*)Bs + brow[n] + foff1);
        #pragma unroll
        for (int m = 0; m < 4; m++)
            #pragma unroll
            for (int n = 0; n < 4; n++)
                acc[m][n] = __builtin_amdgcn_mfma_f32_16x16x32_bf16(af[m], bf[n], acc[m][n], 0, 0, 0);

        __syncthreads();
    }

    #pragma unroll
    for (int n = 0; n < 4; n++) {
        const int col = n0 + wc * 64 + n * 16 + lr;
        const float bv = BIAS ? bias[col] : 0.0f;
        #pragma unroll
        for (int m = 0; m < 4; m++) {
            const int rb = m0 + wr * 64 + m * 16 + lg * 4;
            #pragma unroll
            for (int j = 0; j < 4; j++) {
                float v = acc[m][n][j] + bv;
                if (RELU) v = fmaxf(v, 0.f);
                const size_t row = (size_t)(rb + j);
                if (RESID) v += R[row * ldr + col];
                if (OMODE == 0) {
                    ((float*)Cv)[row * ldc + col] = v;
                } else {
                    ((unsigned short*)Cv)[row * ldc + col] = f2bf(v);
                }
            }
        }
    }
}

// ---------------------------------------------------------------------------
// MFMA attention over fused QKV [32768][1536] bf16. XCD-swizzled so the 4 qt
// blocks of one (h,b) co-locate on one XCD (K/V L2 reuse). No W0 write here;
// only rowsums (h==0) for the sw0 kernel.
// ---------------------------------------------------------------------------
__global__ __launch_bounds__(256, 3) void attn_mfma(
    const unsigned short* __restrict__ QKV,
    const float* __restrict__ tb,
    unsigned short* __restrict__ AOb,       // [32768][512] bf16
    float* __restrict__ lgout)              // [32768] rowsums (h==0)
{
    const int flat = blockIdx.x + 4 * (blockIdx.y + 4 * blockIdx.z);  // 0..1023
    const int logical = ((flat & 7) << 7) + (flat >> 3);
    const int qt = logical & 3;
    const int h  = (logical >> 2) & 3;
    const int b  = logical >> 4;
    const int t  = threadIdx.x;
    const int w  = t >> 6, l = t & 63;
    const int lr = l & 15, lg = l >> 4;
    const int qbase = qt * 128 + w * 32;

    const unsigned short* Qp = QKV;
    const unsigned short* Kp = QKV + 512;
    const unsigned short* Vp = QKV + 1024;

    __shared__ __align__(16) unsigned short Ks[64 * 128];
    __shared__ __align__(16) unsigned short Vt[128 * 64];
    __shared__ __align__(16) unsigned short Pl[4 * 2048];
    __shared__ float tbs[512];

    tbs[t] = tb[t];
    tbs[t + 256] = tb[t + 256];

    short8 qf[2][4];
    #pragma unroll
    for (int fc = 0; fc < 2; fc++) {
        const size_t qrow = (size_t)(b * LSEQ + qbase + fc * 16 + lr) * LDQKV + h * HDIM;
        #pragma unroll
        for (int ks = 0; ks < 4; ks++)
            qf[fc][ks] = *(const short8*)(Qp + qrow + ks * 32 + lg * 8);
    }

    f32x4 oacc[2][8];
    #pragma unroll
    for (int m = 0; m < 2; m++)
        #pragma unroll
        for (int n = 0; n < 8; n++)
            oacc[m][n] = (f32x4){0.f, 0.f, 0.f, 0.f};
    float lpart[2] = {0.f, 0.f};

    const float scale = 0.08838834764831845f;  // 1/sqrt(128)
    unsigned short* Plw = Pl + w * 2048;

    for (int kt = 0; kt < 8; ++kt) {
        __syncthreads();

        const int k0 = (l & 31) * 2;
        const int d0 = w * 32 + (l >> 5) * 16;
        const size_t vrow = (size_t)(b * LSEQ + kt * 64 + k0) * LDQKV + h * HDIM + d0;
        short8 va0 = *(const short8*)(Vp + vrow);
        short8 va1 = *(const short8*)(Vp + vrow + 8);
        short8 vb0 = *(const short8*)(Vp + vrow + LDQKV);
        short8 vb1 = *(const short8*)(Vp + vrow + LDQKV + 8);

        #pragma unroll
        for (int it = 0; it < 4; it++) {
            const int bi = it * 4 + w;
            const int r  = bi * 4 + lg;
            const int sc = lr ^ (r & 7);
            const char* src = (const char*)Kp +
                (size_t)(b * LSEQ + kt * 64 + r) * (LDQKV * 2) + h * 256 + sc * 16;
            load16_lds(src, (char*)Ks + bi * 1024);
        }

        #pragma unroll
        for (int j = 0; j < 16; j++) {
            const int d = d0 + j;
            unsigned short lo = (unsigned short)((j < 8) ? va0[j] : va1[j - 8]);
            unsigned short hi = (unsigned short)((j < 8) ? vb0[j] : vb1[j - 8]);
            unsigned int pk = (unsigned)lo | ((unsigned)hi << 16);
            const int addr = d * 128 + ((((k0 >> 3) ^ (d & 7))) << 4) + (k0 & 7) * 2;
            *(unsigned int*)((char*)Vt + addr) = pk;
        }
        __syncthreads();

        f32x4 sacc[4][2];
        #pragma unroll
        for (int fm = 0; fm < 4; fm++)
            #pragma unroll
            for (int fc = 0; fc < 2; fc++)
                sacc[fm][fc] = (f32x4){0.f, 0.f, 0.f, 0.f};
        #pragma unroll
        for (int ks = 0; ks < 4; ks++) {
            short8 af[4];
            #pragma unroll
            for (int fm = 0; fm < 4; fm++) {
                const int r2 = fm * 16 + lr;
                af[fm] = *(const short8*)((const char*)Ks +
                          r2 * 256 + (((ks * 4 + lg) ^ (lr & 7)) << 4));
            }
            #pragma unroll
            for (int fm = 0; fm < 4; fm++)
                #pragma unroll
                for (int fc = 0; fc < 2; fc++)
                    sacc[fm][fc] = __builtin_amdgcn_mfma_f32_16x16x32_bf16(
                        af[fm], qf[fc][ks], sacc[fm][fc], 0, 0, 0);
        }

        #pragma unroll
        for (int fm = 0; fm < 4; fm++) {
            #pragma unroll
            for (int fc = 0; fc < 2; fc++) {
                float p0 = sacc[fm][fc][0] * scale;
                float p1 = sacc[fm][fc][1] * scale;
                float p2 = sacc[fm][fc][2] * scale;
                float p3 = sacc[fm][fc][3] * scale;
                if (qt == 0 && w == 0 && fc == 0 && lr == 0) {
                    const int kb = kt * 64 + fm * 16 + lg * 4;
                    p0 += tbs[kb + 0]; p1 += tbs[kb + 1];
                    p2 += tbs[kb + 2]; p3 += tbs[kb + 3];
                }
                p0 = __expf(p0); p1 = __expf(p1);
                p2 = __expf(p2); p3 = __expf(p3);
                lpart[fc] += (p0 + p1) + (p2 + p3);
                const int rq = fc * 16 + lr;
                const int chunk = fm * 2 + (lg >> 1);
                const int addr = rq * 128 + ((chunk ^ (rq & 7)) << 4) + (lg & 1) * 8;
                unsigned int lo = (unsigned)f2bf(p0) | ((unsigned)f2bf(p1) << 16);
                unsigned int hi = (unsigned)f2bf(p2) | ((unsigned)f2bf(p3) << 16);
                *(uint2*)((char*)Plw + addr) = make_uint2(lo, hi);
            }
        }

        #pragma unroll
        for (int ks2 = 0; ks2 < 2; ks2++) {
            short8 pf[2];
            #pragma unroll
            for (int fm2 = 0; fm2 < 2; fm2++) {
                const int rq2 = fm2 * 16 + lr;
                pf[fm2] = *(const short8*)((const char*)Plw +
                           rq2 * 128 + (((ks2 * 4 + lg) ^ (rq2 & 7)) << 4));
            }
            #pragma unroll
            for (int fn = 0; fn < 8; fn++) {
                const int d = fn * 16 + lr;
                short8 vf = *(const short8*)((const char*)Vt +
                             d * 128 + (((ks2 * 4 + lg) ^ (d & 7)) << 4));
                #pragma unroll
                for (int fm2 = 0; fm2 < 2; fm2++)
                    oacc[fm2][fn] = __builtin_amdgcn_mfma_f32_16x16x32_bf16(
                        pf[fm2], vf, oacc[fm2][fn], 0, 0, 0);
            }
        }
    }

    float l0 = lpart[0], l1 = lpart[1];
    l0 += __shfl_xor(l0, 16); l0 += __shfl_xor(l0, 32);
    l1 += __shfl_xor(l1, 16); l1 += __shfl_xor(l1, 32);
    float* lw = (float*)Plw;
    if (lg == 0) { lw[lr] = l0; lw[16 + lr] = l1; }
    if (h == 0 && lg == 0) {
        lgout[b * LSEQ + qbase + lr]      = l0;
        lgout[b * LSEQ + qbase + 16 + lr] = l1;
    }
    __builtin_amdgcn_s_waitcnt(0);

    #pragma unroll
    for (int fm2 = 0; fm2 < 2; fm2++) {
        float linv[4];
        #pragma unroll
        for (int j = 0; j < 4; j++)
            linv[j] = 1.0f / lw[fm2 * 16 + lg * 4 + j];
        #pragma unroll
        for (int fn = 0; fn < 8; fn++) {
            const int d = fn * 16 + lr;
            #pragma unroll
            for (int j = 0; j < 4; j++) {
                const int q = qbase + fm2 * 16 + lg * 4 + j;
                AOb[(size_t)(b * LSEQ + q) * SDIM + h * HDIM + d] =
                    f2bf(oacc[fm2][fn][j] * linv[j]);
            }
        }
    }
}

// ---------------------------------------------------------------------------
// sw0: recompute h=0 scores, write NORMALIZED attn_weights[:,0] fp32 directly.
// Same MFMA/exp order as attn_mfma -> p matches lgout exactly.
// Grid (4 qt, 64 b), XCD-swizzled.
// ---------------------------------------------------------------------------
__global__ __launch_bounds__(256) void sw0_kernel(
    const unsigned short* __restrict__ QKV,
    const float* __restrict__ tb,
    const float* __restrict__ lsum,
    float* __restrict__ W0)
{
    const int flat = blockIdx.x + 4 * blockIdx.y;   // 0..255
    const int logical = ((flat & 7) << 5) + (flat >> 3);
    const int qt = logical & 3;
    const int b  = logical >> 2;
    const int t  = threadIdx.x;
    const int w  = t >> 6, l = t & 63;
    const int lr = l & 15, lg = l >> 4;
    const int qbase = qt * 128 + w * 32;

    const unsigned short* Qp = QKV;
    const unsigned short* Kp = QKV + 512;

    __shared__ __align__(16) unsigned short Ks[64 * 128];

    short8 qf[2][4];
    #pragma unroll
    for (int fc = 0; fc < 2; fc++) {
        const size_t qrow = (size_t)(b * LSEQ + qbase + fc * 16 + lr) * LDQKV;
        #pragma unroll
        for (int ks = 0; ks < 4; ks++)
            qf[fc][ks] = *(const short8*)(Qp + qrow + ks * 32 + lg * 8);
    }

    float linv[2];
    linv[0] = 1.0f / lsum[b * LSEQ + qbase + lr];
    linv[1] = 1.0f / lsum[b * LSEQ + qbase + 16 + lr];

    const float scale = 0.08838834764831845f;

    for (int kt = 0; kt < 8; ++kt) {
        __syncthreads();
        #pragma unroll
        for (int it = 0; it < 4; it++) {
            const int bi = it * 4 + w;
            const int r  = bi * 4 + lg;
            const int sc = lr ^ (r & 7);
            const char* src = (const char*)Kp +
                (size_t)(b * LSEQ + kt * 64 + r) * (LDQKV * 2) + sc * 16;
            load16_lds(src, (char*)Ks + bi * 1024);
        }
        __syncthreads();

        f32x4 sacc[4][2];
        #pragma unroll
        for (int fm = 0; fm < 4; fm++)
            #pragma unroll
            for (int fc = 0; fc < 2; fc++)
                sacc[fm][fc] = (f32x4){0.f, 0.f, 0.f, 0.f};
        #pragma unroll
        for (int ks = 0; ks < 4; ks++) {
            short8 af[4];
            #pragma unroll
            for (int fm = 0; fm < 4; fm++) {
                const int r2 = fm * 16 + lr;
                af[fm] = *(const short8*)((const char*)Ks +
                          r2 * 256 + (((ks * 4 + lg) ^ (lr & 7)) << 4));
            }
            #pragma unroll
            for (int fm = 0; fm < 4; fm++)
                #pragma unroll
                for (int fc = 0; fc < 2; fc++)
                    sacc[fm][fc] = __builtin_amdgcn_mfma_f32_16x16x32_bf16(
                        af[fm], qf[fc][ks], sacc[fm][fc], 0, 0, 0);
        }

        #pragma unroll
        for (int fm = 0; fm < 4; fm++) {
            #pragma unroll
            for (int fc = 0; fc < 2; fc++) {
                float p0 = sacc[fm][fc][0] * scale;
                float p1 = sacc[fm][fc][1] * scale;
                float p2 = sacc[fm][fc][2] * scale;
                float p3 = sacc[fm][fc][3] * scale;
                if (qt == 0 && w == 0 && fc == 0 && lr == 0) {
                    const int kb = kt * 64 + fm * 16 + lg * 4;
                    p0 += tb[kb + 0]; p1 += tb[kb + 1];
                    p2 += tb[kb + 2]; p3 += tb[kb + 3];
                }
                p0 = __expf(p0) * linv[fc]; p1 = __expf(p1) * linv[fc];
                p2 = __expf(p2) * linv[fc]; p3 = __expf(p3) * linv[fc];
                const int q = qbase + fc * 16 + lr;
                float* dst = W0 + (size_t)(b * LSEQ + q) * LSEQ +
                             kt * 64 + fm * 16 + lg * 4;
                *(float4*)dst = make_float4(p0, p1, p2, p3);
            }
        }
    }
}

// ---------------------------------------------------------------------------
extern "C" void kernel_launch(void* const* d_in, const int* in_sizes, int n_in,
                              void* d_out, int out_size, void* d_ws, size_t ws_size,
                              hipStream_t stream)
{
    const float* s   = (const float*)d_in[0];
    const float* z   = (const float*)d_in[1];
    const float* wq  = (const float*)d_in[2];
    const float* bq  = (const float*)d_in[3];
    const float* wk  = (const float*)d_in[4];
    const float* bk  = (const float*)d_in[5];
    const float* wv  = (const float*)d_in[6];
    const float* bv  = (const float*)d_in[7];
    const float* wo  = (const float*)d_in[8];
    const float* bo  = (const float*)d_in[9];
    const float* wp  = (const float*)d_in[10];
    const float* bp  = (const float*)d_in[11];
    const float* pos = (const float*)d_in[12];
    const float* ew  = (const float*)d_in[13];
    const float* lng = (const float*)d_in[14];
    const float* lnb = (const float*)d_in[15];
    const float* w1  = (const float*)d_in[16];
    const float* b1  = (const float*)d_in[17];
    const float* w2  = (const float*)d_in[18];
    const float* b2  = (const float*)d_in[19];

    float* out = (float*)d_out;
    const size_t oz  = (size_t)NROWS * SDIM;
    const size_t ow  = oz + (size_t)NROWS * 64;
    const size_t ope = ow + (size_t)NROWS * LSEQ;
    const size_t opr = ope + (size_t)NROWS;

    // workspace layout (bytes)
    char* wsb = (char*)d_ws;
    unsigned short* QKV = (unsigned short*)(wsb);             // [32768][1536] bf16, 96MB
    float*          s2f = (float*)(wsb);                      // s2 fp32 64MB (after attn)
    unsigned short* hb  = (unsigned short*)(wsb + 67108864);  // LN2 bf16 32MB (after attn)
    unsigned short* Xb  = (unsigned short*)(wsb + 100663296); // s_ln bf16 -> attn_out bf16
    unsigned short* F   = (unsigned short*)(wsb + 100663296); // FFN mid [32768][2048] bf16 (after WO)
    unsigned short* wqkvt = (unsigned short*)(wsb + 234881024);
    unsigned short* wot = wqkvt + 786432;
    unsigned short* w1t = wqkvt + 1048576;    // [2048][512]
    unsigned short* w2t = wqkvt + 2097152;    // [512][2048]
    unsigned short* wpT = wqkvt + 3145728;    // [32][512]
    float* bqkv = (float*)(wsb + 234881024 + 6324224);
    float* tb   = bqkv + 1536;
    float* lgv  = tb + 512;

    // 0. weight prep
    wtrans<<<dim3(16, 16), 256, 0, stream>>>(wq, wqkvt, 512, 512);
    wtrans<<<dim3(16, 16), 256, 0, stream>>>(wk, wqkvt + 262144, 512, 512);
    wtrans<<<dim3(16, 16), 256, 0, stream>>>(wv, wqkvt + 524288, 512, 512);
    wtrans<<<dim3(16, 16), 256, 0, stream>>>(wo, wot, 512, 512);
    wtrans<<<dim3(64, 16), 256, 0, stream>>>(w1, w1t, 512, 2048);
    wtrans<<<dim3(16, 64), 256, 0, stream>>>(w2, w2t, 2048, 512);
    wptrans<<<64, 256, 0, stream>>>(wp, wpT);
    bpack<<<1, 512, 0, stream>>>(bq, bk, bv, bqkv);

    // 1. LN(s) -> bf16 Xb
    ln_kernel<false><<<NROWS, 256, 0, stream>>>(s, Xb, nullptr, nullptr);

    // 1b. profile softmax + entropy (MFMA)
    profile_kernel<<<256, 256, 0, stream>>>(Xb, wpT, bp, out + opr, out + ope);

    // 2. total bias from batch-0 entropy
    bias_kernel<<<1, 512, 0, stream>>>(out + ope, ew, pos, tb);

    // 3. fused QKV projection -> QKV bf16 [32768][1536]
    mgemm<1, true, false, false><<<dim3(12, 256), 256, 0, stream>>>(
        Xb, 512, wqkvt, 512, QKV, LDQKV, bqkv, nullptr, 0, 512);

    // 4. MFMA attention -> attn_out bf16 (Xb) + rowsums
    attn_mfma<<<dim3(4, NHEAD, BATCH), 256, 0, stream>>>(
        QKV, tb, Xb, lgv);

    // 4b. head-0 normalized attention weights (fp32)
    sw0_kernel<<<dim3(4, BATCH), 256, 0, stream>>>(QKV, tb, lgv, out + ow);

    // 5. s2 = s + attn_out @ wo + bo  (fp32 into s2f)
    mgemm<0, true, false, true><<<dim3(4, 256), 256, 0, stream>>>(
        Xb, 512, wot, 512, s2f, 512, bo, s, 512, 512);

    // 6. h = LN(s2)*g + b -> bf16
    ln_kernel<true><<<NROWS, 256, 0, stream>>>(s2f, hb, lng, lnb);

    // 7. FFN1: F = relu(h @ w1 + b1), bf16 [32768][2048]
    mgemm<1, true, true, false><<<dim3(16, 256), 256, 0, stream>>>(
        hb, 512, w1t, 512, F, 2048, b1, nullptr, 0, 512);

    // 8. FFN2: out0 = F @ w2 + b2 + s2
    mgemm<0, true, false, true><<<dim3(4, 256), 256, 0, stream>>>(
        F, 2048, w2t, 2048, out, 512, b2, s2f, 512, 2048);

    // 9. z passthrough
    hipMemcpyAsync(out + oz, z, (size_t)NROWS * 64 * sizeof(float),
                   hipMemcpyDeviceToDevice, stream);
}

// Round 6
// 502.807 us; speedup vs baseline: 9.3413x; 1.1096x over previous
//
#include <hip/hip_runtime.h>
#include <hip/hip_bf16.h>
#include <math.h>

// Problem constants
#define SDIM 512
#define BATCH 64
#define LSEQ 512
#define NHEAD 4
#define HDIM 128
#define NAA 20
#define NROWS (BATCH * LSEQ)   // 32768
#define LDQKV 1536

typedef __attribute__((ext_vector_type(8))) short short8;
typedef __attribute__((ext_vector_type(4))) float f32x4;

__device__ __forceinline__ unsigned short f2bf(float f) {
    unsigned int x = __float_as_uint(f);
    unsigned int r = (x + 0x7fffu + ((x >> 16) & 1u)) >> 16;  // RNE
    return (unsigned short)r;
}

__device__ __forceinline__ void load16_lds(const void* g, void* lds) {
    __builtin_amdgcn_global_load_lds(
        (const __attribute__((address_space(1))) unsigned int*)g,
        (__attribute__((address_space(3))) unsigned int*)lds, 16, 0, 0);
}

// ---------------------------------------------------------------------------
// Weight transpose + bf16 convert: W[K][N] fp32 -> Wt[N][K] bf16
// ---------------------------------------------------------------------------
__global__ __launch_bounds__(256) void wtrans(
    const float* __restrict__ W, unsigned short* __restrict__ Wt, int K, int N)
{
    __shared__ float tile[32][33];
    const int t = threadIdx.x, tx = t & 31, ty = t >> 5;
    const int n0 = blockIdx.x * 32, k0 = blockIdx.y * 32;
    #pragma unroll
    for (int p = 0; p < 4; p++)
        tile[ty + p * 8][tx] = W[(size_t)(k0 + ty + p * 8) * N + n0 + tx];
    __syncthreads();
    #pragma unroll
    for (int p = 0; p < 4; p++)
        Wt[(size_t)(n0 + ty + p * 8) * K + k0 + tx] = f2bf(tile[tx][ty + p * 8]);
}

// wp [512][20] fp32 -> wpT [32][512] bf16, rows 20..31 zero
__global__ __launch_bounds__(256) void wptrans(
    const float* __restrict__ wp, unsigned short* __restrict__ wpT)
{
    const int g = blockIdx.x * 256 + threadIdx.x;   // 64 blocks -> 16384
    const int k = g & 511, j = g >> 9;
    float v = (j < NAA) ? wp[(size_t)k * NAA + j] : 0.0f;
    wpT[(size_t)j * 512 + k] = f2bf(v);
}

// pack bq|bk|bv into one 1536 vector
__global__ void bpack(const float* __restrict__ bq, const float* __restrict__ bk,
                      const float* __restrict__ bv, float* __restrict__ bqkv)
{
    int t = threadIdx.x;  // 512
    bqkv[t] = bq[t]; bqkv[512 + t] = bk[t]; bqkv[1024 + t] = bv[t];
}

// ---------------------------------------------------------------------------
// LayerNorm (bf16 out), optional affine. One block per row.
// ---------------------------------------------------------------------------
template<bool AFFINE>
__global__ __launch_bounds__(256) void ln_kernel(
    const float* __restrict__ in, unsigned short* __restrict__ out,
    const float* __restrict__ gamma, const float* __restrict__ beta)
{
    const int r = blockIdx.x;
    const int t = threadIdx.x;
    const int wave = t >> 6, lane = t & 63;
    const float* row = in + (size_t)r * SDIM;

    float2 v = *(const float2*)(row + t * 2);
    float sum = v.x + v.y;
    float sq  = v.x * v.x + v.y * v.y;
    #pragma unroll
    for (int o = 32; o > 0; o >>= 1) {
        sum += __shfl_down(sum, o);
        sq  += __shfl_down(sq, o);
    }
    __shared__ float red[8];
    __shared__ float mb[2];
    if (lane == 0) { red[wave] = sum; red[4 + wave] = sq; }
    __syncthreads();
    if (t == 0) {
        float s_ = red[0] + red[1] + red[2] + red[3];
        float q_ = red[4] + red[5] + red[6] + red[7];
        float mean = s_ * (1.0f / SDIM);
        float var  = q_ * (1.0f / SDIM) - mean * mean;
        mb[0] = mean;
        mb[1] = rsqrtf(var + 1e-5f);
    }
    __syncthreads();
    const float mean = mb[0], inv = mb[1];
    float o0 = (v.x - mean) * inv;
    float o1 = (v.y - mean) * inv;
    if (AFFINE) {
        o0 = o0 * gamma[t * 2]     + beta[t * 2];
        o1 = o1 * gamma[t * 2 + 1] + beta[t * 2 + 1];
    }
    unsigned int pk = (unsigned)f2bf(o0) | ((unsigned)f2bf(o1) << 16);
    *(unsigned int*)(out + (size_t)r * SDIM + t * 2) = pk;
}

// ---------------------------------------------------------------------------
// Profile kernel: logits = s_ln(bf16) @ wpT^T + bp, softmax+entropy epilogue.
// ---------------------------------------------------------------------------
__global__ __launch_bounds__(256) void profile_kernel(
    const unsigned short* __restrict__ A,     // [32768][512] bf16
    const unsigned short* __restrict__ wpT,   // [32][512] bf16 (zero-padded)
    const float* __restrict__ bp,             // [20]
    float* __restrict__ probs,                // [32768][20]
    float* __restrict__ pe)                   // [32768]
{
    __shared__ __align__(16) unsigned short As[128 * 64];

    const int t = threadIdx.x;
    const int w = t >> 6, l = t & 63;
    const int lr = l & 15, lg = l >> 4;
    const int m0 = blockIdx.x * 128;

    f32x4 sacc[2][2];
    #pragma unroll
    for (int m = 0; m < 2; m++)
        #pragma unroll
        for (int n = 0; n < 2; n++)
            sacc[m][n] = (f32x4){0.f, 0.f, 0.f, 0.f};

    const int srow  = l >> 3;
    const int swz16 = ((l & 7) ^ srow) << 4;
    const char* pA[4];
    unsigned ldsoff[4];
    #pragma unroll
    for (int i = 0; i < 4; i++) {
        const int row = (w * 4 + i) * 8 + srow;
        pA[i] = (const char*)A + (size_t)(m0 + row) * 1024 + swz16;
        ldsoff[i] = (unsigned)(w * 4 + i) * 1024;
    }

    const int rsw   = (lr & 7) << 4;
    const int foff0 = (lg * 16) ^ rsw;
    const int foff1 = (64 + lg * 16) ^ rsw;
    int arow[2];
    #pragma unroll
    for (int m = 0; m < 2; m++) arow[m] = (w * 32 + m * 16 + lr) * 128;

    for (int k0 = 0; k0 < 512; k0 += 64) {
        const size_t kb = (size_t)k0 * 2;
        #pragma unroll
        for (int i = 0; i < 4; i++)
            load16_lds(pA[i] + kb, (char*)As + ldsoff[i]);
        __syncthreads();

        short8 af[2], bf[2];
        #pragma unroll
        for (int m = 0; m < 2; m++) af[m] = *(const short8*)((const char*)As + arow[m] + foff0);
        #pragma unroll
        for (int n = 0; n < 2; n++)
            bf[n] = *(const short8*)(wpT + (size_t)(n * 16 + lr) * 512 + k0 + lg * 8);
        #pragma unroll
        for (int m = 0; m < 2; m++)
            #pragma unroll
            for (int n = 0; n < 2; n++)
                sacc[m][n] = __builtin_amdgcn_mfma_f32_16x16x32_bf16(af[m], bf[n], sacc[m][n], 0, 0, 0);

        #pragma unroll
        for (int m = 0; m < 2; m++) af[m] = *(const short8*)((const char*)As + arow[m] + foff1);
        #pragma unroll
        for (int n = 0; n < 2; n++)
            bf[n] = *(const short8*)(wpT + (size_t)(n * 16 + lr) * 512 + k0 + 32 + lg * 8);
        #pragma unroll
        for (int m = 0; m < 2; m++)
            #pragma unroll
            for (int n = 0; n < 2; n++)
                sacc[m][n] = __builtin_amdgcn_mfma_f32_16x16x32_bf16(af[m], bf[n], sacc[m][n], 0, 0, 0);

        __syncthreads();
    }

    const float b0 = bp[lr];
    const float b1 = (lr < 4) ? bp[16 + lr] : 0.0f;
    #pragma unroll
    for (int m = 0; m < 2; m++) {
        #pragma unroll
        for (int j = 0; j < 4; j++) {
            const float v0 = sacc[m][0][j] + b0;
            const float e0 = __expf(v0);
            const float v1 = sacc[m][1][j] + b1;
            const float e1 = (lr < 4) ? __expf(v1) : 0.0f;
            float Sp = e0 + e1;
            float Tp = e0 * v0 + ((lr < 4) ? e1 * v1 : 0.0f);
            #pragma unroll
            for (int o = 1; o < 16; o <<= 1) {
                Sp += __shfl_xor(Sp, o);
                Tp += __shfl_xor(Tp, o);
            }
            const float inv = 1.0f / Sp;
            const int row = m0 + w * 32 + m * 16 + lg * 4 + j;
            probs[(size_t)row * NAA + lr] = e0 * inv;
            if (lr < 4) probs[(size_t)row * NAA + 16 + lr] = e1 * inv;
            if (lr == 0) pe[row] = logf(Sp) - Tp * inv;
        }
    }
}

// total_bias[m] = -pe[0,m]*ew + pos_bias[m]
__global__ void bias_kernel(const float* __restrict__ pe,
                            const float* __restrict__ ew,
                            const float* __restrict__ pos,
                            float* __restrict__ tb)
{
    int t = threadIdx.x;  // 512 threads
    tb[t] = -pe[t] * ew[0] + pos[t];
}

// ---------------------------------------------------------------------------
// bf16 MFMA GEMM, 2-deep software pipeline (T3/T4 minimal):
// double-buffered 64KB LDS, counted vmcnt (8 = next tile in flight), raw
// s_barrier (no compiler vmcnt(0) drain), setprio around MFMA clusters.
// ---------------------------------------------------------------------------
template<int OMODE, bool BIAS, bool RELU, bool RESID>
__global__ __launch_bounds__(256) void mgemm(
    const unsigned short* __restrict__ A, int lda,
    const unsigned short* __restrict__ Bt, int ldb,
    void* __restrict__ Cv, int ldc,
    const float* __restrict__ bias,
    const float* __restrict__ R, int ldr,
    int K)
{
    // 2 buffers x (As 16KB + Bs 16KB) = 64KB
    __shared__ __align__(16) unsigned short lds[32768];

    const int t = threadIdx.x;
    const int w = t >> 6, l = t & 63;
    const int wr = w >> 1, wc = w & 1;

    // XCD swizzle: contiguous logical chunk per XCD (nwg % 8 == 0 for all grids)
    const int gx   = gridDim.x;
    const int nwg  = gx * gridDim.y;
    const int flat = blockIdx.x + gx * blockIdx.y;
    const int cpx  = nwg >> 3;
    const int logical = (flat & 7) * cpx + (flat >> 3);
    const int m0 = (logical / gx) * 128, n0 = (logical % gx) * 128;

    f32x4 acc[4][4];
    #pragma unroll
    for (int m = 0; m < 4; m++)
        #pragma unroll
        for (int n = 0; n < 4; n++)
            acc[m][n] = (f32x4){0.f, 0.f, 0.f, 0.f};

    const int srow  = l >> 3;
    const int swz16 = ((l & 7) ^ srow) << 4;
    const char* pA[4];
    const char* pB[4];
    unsigned ldsoff[4];
    #pragma unroll
    for (int i = 0; i < 4; i++) {
        const int row = (w * 4 + i) * 8 + srow;
        pA[i] = (const char*)A  + (size_t)(m0 + row) * (lda * 2) + swz16;
        pB[i] = (const char*)Bt + (size_t)(n0 + row) * (ldb * 2) + swz16;
        ldsoff[i] = (unsigned)(w * 4 + i) * 1024;
    }

    const int lg = l >> 4;
    const int lr = l & 15;
    int arow[4], brow[4];
    #pragma unroll
    for (int m = 0; m < 4; m++) arow[m] = (wr * 64 + m * 16 + lr) * 128;
    #pragma unroll
    for (int n = 0; n < 4; n++) brow[n] = (wc * 64 + n * 16 + lr) * 128;
    const int rsw   = (lr & 7) << 4;
    const int foff0 = (lg * 16) ^ rsw;
    const int foff1 = (64 + lg * 16) ^ rsw;

    const int nt = K >> 6;   // K-tiles of 64 (always even here: 8 or 32, min 8)

    auto issue = [&](int kt, int bufb) {
        const size_t kb = (size_t)kt * 128;   // bytes
        #pragma unroll
        for (int i = 0; i < 4; i++) {
            load16_lds(pA[i] + kb, (char*)lds + bufb + ldsoff[i]);
            load16_lds(pB[i] + kb, (char*)lds + bufb + 16384 + ldsoff[i]);
        }
    };

    issue(0, 0);
    issue(1, 32768);

    auto body = [&](int kt, int bufb) {
        // wait for tile kt (8 loads of tile kt+1 may stay in flight)
        if (kt + 1 < nt) { asm volatile("s_waitcnt vmcnt(8)" ::: "memory"); }
        else             { asm volatile("s_waitcnt vmcnt(0)" ::: "memory"); }
        __builtin_amdgcn_s_barrier();
        asm volatile("" ::: "memory");

        const char* Ab = (const char*)lds + bufb;
        const char* Bb = (const char*)lds + bufb + 16384;
        short8 af[4], bf[4];
        #pragma unroll
        for (int m = 0; m < 4; m++) af[m] = *(const short8*)(Ab + arow[m] + foff0);
        #pragma unroll
        for (int n = 0; n < 4; n++) bf[n] = *(const short8*)(Bb + brow[n] + foff0);
        __builtin_amdgcn_s_setprio(1);
        #pragma unroll
        for (int m = 0; m < 4; m++)
            #pragma unroll
            for (int n = 0; n < 4; n++)
                acc[m][n] = __builtin_amdgcn_mfma_f32_16x16x32_bf16(af[m], bf[n], acc[m][n], 0, 0, 0);
        __builtin_amdgcn_s_setprio(0);

        #pragma unroll
        for (int m = 0; m < 4; m++) af[m] = *(const short8*)(Ab + arow[m] + foff1);
        #pragma unroll
        for (int n = 0; n < 4; n++) bf[n] = *(const short8*)(Bb + brow[n] + foff1);
        __builtin_amdgcn_s_setprio(1);
        #pragma unroll
        for (int m = 0; m < 4; m++)
            #pragma unroll
            for (int n = 0; n < 4; n++)
                acc[m][n] = __builtin_amdgcn_mfma_f32_16x16x32_bf16(af[m], bf[n], acc[m][n], 0, 0, 0);
        __builtin_amdgcn_s_setprio(0);

        asm volatile("" ::: "memory");
        __builtin_amdgcn_s_barrier();
        asm volatile("" ::: "memory");
        // buffer bufb fully consumed by all waves -> refill with tile kt+2
        if (kt + 2 < nt) issue(kt + 2, bufb);
    };

    for (int kt = 0; kt < nt; kt += 2) {
        body(kt, 0);
        body(kt + 1, 32768);
    }

    #pragma unroll
    for (int n = 0; n < 4; n++) {
        const int col = n0 + wc * 64 + n * 16 + lr;
        const float bv = BIAS ? bias[col] : 0.0f;
        #pragma unroll
        for (int m = 0; m < 4; m++) {
            const int rb = m0 + wr * 64 + m * 16 + lg * 4;
            #pragma unroll
            for (int j = 0; j < 4; j++) {
                float v = acc[m][n][j] + bv;
                if (RELU) v = fmaxf(v, 0.f);
                const size_t row = (size_t)(rb + j);
                if (RESID) v += R[row * ldr + col];
                if (OMODE == 0) {
                    ((float*)Cv)[row * ldc + col] = v;
                } else {
                    ((unsigned short*)Cv)[row * ldc + col] = f2bf(v);
                }
            }
        }
    }
}

// ---------------------------------------------------------------------------
// MFMA attention over fused QKV [32768][1536] bf16. XCD-swizzled so the 4 qt
// blocks of one (h,b) co-locate on one XCD (K/V L2 reuse). No W0 write here;
// only rowsums (h==0) for the sw0 kernel.
// ---------------------------------------------------------------------------
__global__ __launch_bounds__(256, 3) void attn_mfma(
    const unsigned short* __restrict__ QKV,
    const float* __restrict__ tb,
    unsigned short* __restrict__ AOb,       // [32768][512] bf16
    float* __restrict__ lgout)              // [32768] rowsums (h==0)
{
    const int flat = blockIdx.x + 4 * (blockIdx.y + 4 * blockIdx.z);  // 0..1023
    const int logical = ((flat & 7) << 7) + (flat >> 3);
    const int qt = logical & 3;
    const int h  = (logical >> 2) & 3;
    const int b  = logical >> 4;
    const int t  = threadIdx.x;
    const int w  = t >> 6, l = t & 63;
    const int lr = l & 15, lg = l >> 4;
    const int qbase = qt * 128 + w * 32;

    const unsigned short* Qp = QKV;
    const unsigned short* Kp = QKV + 512;
    const unsigned short* Vp = QKV + 1024;

    __shared__ __align__(16) unsigned short Ks[64 * 128];
    __shared__ __align__(16) unsigned short Vt[128 * 64];
    __shared__ __align__(16) unsigned short Pl[4 * 2048];
    __shared__ float tbs[512];

    tbs[t] = tb[t];
    tbs[t + 256] = tb[t + 256];

    short8 qf[2][4];
    #pragma unroll
    for (int fc = 0; fc < 2; fc++) {
        const size_t qrow = (size_t)(b * LSEQ + qbase + fc * 16 + lr) * LDQKV + h * HDIM;
        #pragma unroll
        for (int ks = 0; ks < 4; ks++)
            qf[fc][ks] = *(const short8*)(Qp + qrow + ks * 32 + lg * 8);
    }

    f32x4 oacc[2][8];
    #pragma unroll
    for (int m = 0; m < 2; m++)
        #pragma unroll
        for (int n = 0; n < 8; n++)
            oacc[m][n] = (f32x4){0.f, 0.f, 0.f, 0.f};
    float lpart[2] = {0.f, 0.f};

    const float scale = 0.08838834764831845f;  // 1/sqrt(128)
    unsigned short* Plw = Pl + w * 2048;

    for (int kt = 0; kt < 8; ++kt) {
        __syncthreads();

        const int k0 = (l & 31) * 2;
        const int d0 = w * 32 + (l >> 5) * 16;
        const size_t vrow = (size_t)(b * LSEQ + kt * 64 + k0) * LDQKV + h * HDIM + d0;
        short8 va0 = *(const short8*)(Vp + vrow);
        short8 va1 = *(const short8*)(Vp + vrow + 8);
        short8 vb0 = *(const short8*)(Vp + vrow + LDQKV);
        short8 vb1 = *(const short8*)(Vp + vrow + LDQKV + 8);

        #pragma unroll
        for (int it = 0; it < 4; it++) {
            const int bi = it * 4 + w;
            const int r  = bi * 4 + lg;
            const int sc = lr ^ (r & 7);
            const char* src = (const char*)Kp +
                (size_t)(b * LSEQ + kt * 64 + r) * (LDQKV * 2) + h * 256 + sc * 16;
            load16_lds(src, (char*)Ks + bi * 1024);
        }

        #pragma unroll
        for (int j = 0; j < 16; j++) {
            const int d = d0 + j;
            unsigned short lo = (unsigned short)((j < 8) ? va0[j] : va1[j - 8]);
            unsigned short hi = (unsigned short)((j < 8) ? vb0[j] : vb1[j - 8]);
            unsigned int pk = (unsigned)lo | ((unsigned)hi << 16);
            const int addr = d * 128 + ((((k0 >> 3) ^ (d & 7))) << 4) + (k0 & 7) * 2;
            *(unsigned int*)((char*)Vt + addr) = pk;
        }
        __syncthreads();

        f32x4 sacc[4][2];
        #pragma unroll
        for (int fm = 0; fm < 4; fm++)
            #pragma unroll
            for (int fc = 0; fc < 2; fc++)
                sacc[fm][fc] = (f32x4){0.f, 0.f, 0.f, 0.f};
        #pragma unroll
        for (int ks = 0; ks < 4; ks++) {
            short8 af[4];
            #pragma unroll
            for (int fm = 0; fm < 4; fm++) {
                const int r2 = fm * 16 + lr;
                af[fm] = *(const short8*)((const char*)Ks +
                          r2 * 256 + (((ks * 4 + lg) ^ (lr & 7)) << 4));
            }
            #pragma unroll
            for (int fm = 0; fm < 4; fm++)
                #pragma unroll
                for (int fc = 0; fc < 2; fc++)
                    sacc[fm][fc] = __builtin_amdgcn_mfma_f32_16x16x32_bf16(
                        af[fm], qf[fc][ks], sacc[fm][fc], 0, 0, 0);
        }

        #pragma unroll
        for (int fm = 0; fm < 4; fm++) {
            #pragma unroll
            for (int fc = 0; fc < 2; fc++) {
                float p0 = sacc[fm][fc][0] * scale;
                float p1 = sacc[fm][fc][1] * scale;
                float p2 = sacc[fm][fc][2] * scale;
                float p3 = sacc[fm][fc][3] * scale;
                if (qt == 0 && w == 0 && fc == 0 && lr == 0) {
                    const int kb = kt * 64 + fm * 16 + lg * 4;
                    p0 += tbs[kb + 0]; p1 += tbs[kb + 1];
                    p2 += tbs[kb + 2]; p3 += tbs[kb + 3];
                }
                p0 = __expf(p0); p1 = __expf(p1);
                p2 = __expf(p2); p3 = __expf(p3);
                lpart[fc] += (p0 + p1) + (p2 + p3);
                const int rq = fc * 16 + lr;
                const int chunk = fm * 2 + (lg >> 1);
                const int addr = rq * 128 + ((chunk ^ (rq & 7)) << 4) + (lg & 1) * 8;
                unsigned int lo = (unsigned)f2bf(p0) | ((unsigned)f2bf(p1) << 16);
                unsigned int hi = (unsigned)f2bf(p2) | ((unsigned)f2bf(p3) << 16);
                *(uint2*)((char*)Plw + addr) = make_uint2(lo, hi);
            }
        }

        #pragma unroll
        for (int ks2 = 0; ks2 < 2; ks2++) {
            short8 pf[2];
            #pragma unroll
            for (int fm2 = 0; fm2 < 2; fm2++) {
                const int rq2 = fm2 * 16 + lr;
                pf[fm2] = *(const short8*)((const char*)Plw +
                           rq2 * 128 + (((ks2 * 4 + lg) ^ (rq2 & 7)) << 4));
            }
            #pragma unroll
            for (int fn = 0; fn < 8; fn++) {
                const int d = fn * 16 + lr;
                short8 vf = *(const short8*)((const char*)Vt +
                             d * 128 + (((ks2 * 4 + lg) ^ (d & 7)) << 4));
                #pragma unroll
                for (int fm2 = 0; fm2 < 2; fm2++)
                    oacc[fm2][fn] = __builtin_amdgcn_mfma_f32_16x16x32_bf16(
                        pf[fm2], vf, oacc[fm2][fn], 0, 0, 0);
            }
        }
    }

    float l0 = lpart[0], l1 = lpart[1];
    l0 += __shfl_xor(l0, 16); l0 += __shfl_xor(l0, 32);
    l1 += __shfl_xor(l1, 16); l1 += __shfl_xor(l1, 32);
    float* lw = (float*)Plw;
    if (lg == 0) { lw[lr] = l0; lw[16 + lr] = l1; }
    if (h == 0 && lg == 0) {
        lgout[b * LSEQ + qbase + lr]      = l0;
        lgout[b * LSEQ + qbase + 16 + lr] = l1;
    }
    __builtin_amdgcn_s_waitcnt(0);

    #pragma unroll
    for (int fm2 = 0; fm2 < 2; fm2++) {
        float linv[4];
        #pragma unroll
        for (int j = 0; j < 4; j++)
            linv[j] = 1.0f / lw[fm2 * 16 + lg * 4 + j];
        #pragma unroll
        for (int fn = 0; fn < 8; fn++) {
            const int d = fn * 16 + lr;
            #pragma unroll
            for (int j = 0; j < 4; j++) {
                const int q = qbase + fm2 * 16 + lg * 4 + j;
                AOb[(size_t)(b * LSEQ + q) * SDIM + h * HDIM + d] =
                    f2bf(oacc[fm2][fn][j] * linv[j]);
            }
        }
    }
}

// ---------------------------------------------------------------------------
// sw0: recompute h=0 scores, write NORMALIZED attn_weights[:,0] fp32 directly.
// ---------------------------------------------------------------------------
__global__ __launch_bounds__(256) void sw0_kernel(
    const unsigned short* __restrict__ QKV,
    const float* __restrict__ tb,
    const float* __restrict__ lsum,
    float* __restrict__ W0)
{
    const int flat = blockIdx.x + 4 * blockIdx.y;   // 0..255
    const int logical = ((flat & 7) << 5) + (flat >> 3);
    const int qt = logical & 3;
    const int b  = logical >> 2;
    const int t  = threadIdx.x;
    const int w  = t >> 6, l = t & 63;
    const int lr = l & 15, lg = l >> 4;
    const int qbase = qt * 128 + w * 32;

    const unsigned short* Qp = QKV;
    const unsigned short* Kp = QKV + 512;

    __shared__ __align__(16) unsigned short Ks[64 * 128];

    short8 qf[2][4];
    #pragma unroll
    for (int fc = 0; fc < 2; fc++) {
        const size_t qrow = (size_t)(b * LSEQ + qbase + fc * 16 + lr) * LDQKV;
        #pragma unroll
        for (int ks = 0; ks < 4; ks++)
            qf[fc][ks] = *(const short8*)(Qp + qrow + ks * 32 + lg * 8);
    }

    float linv[2];
    linv[0] = 1.0f / lsum[b * LSEQ + qbase + lr];
    linv[1] = 1.0f / lsum[b * LSEQ + qbase + 16 + lr];

    const float scale = 0.08838834764831845f;

    for (int kt = 0; kt < 8; ++kt) {
        __syncthreads();
        #pragma unroll
        for (int it = 0; it < 4; it++) {
            const int bi = it * 4 + w;
            const int r  = bi * 4 + lg;
            const int sc = lr ^ (r & 7);
            const char* src = (const char*)Kp +
                (size_t)(b * LSEQ + kt * 64 + r) * (LDQKV * 2) + sc * 16;
            load16_lds(src, (char*)Ks + bi * 1024);
        }
        __syncthreads();

        f32x4 sacc[4][2];
        #pragma unroll
        for (int fm = 0; fm < 4; fm++)
            #pragma unroll
            for (int fc = 0; fc < 2; fc++)
                sacc[fm][fc] = (f32x4){0.f, 0.f, 0.f, 0.f};
        #pragma unroll
        for (int ks = 0; ks < 4; ks++) {
            short8 af[4];
            #pragma unroll
            for (int fm = 0; fm < 4; fm++) {
                const int r2 = fm * 16 + lr;
                af[fm] = *(const short8*)((const char*)Ks +
                          r2 * 256 + (((ks * 4 + lg) ^ (lr & 7)) << 4));
            }
            #pragma unroll
            for (int fm = 0; fm < 4; fm++)
                #pragma unroll
                for (int fc = 0; fc < 2; fc++)
                    sacc[fm][fc] = __builtin_amdgcn_mfma_f32_16x16x32_bf16(
                        af[fm], qf[fc][ks], sacc[fm][fc], 0, 0, 0);
        }

        #pragma unroll
        for (int fm = 0; fm < 4; fm++) {
            #pragma unroll
            for (int fc = 0; fc < 2; fc++) {
                float p0 = sacc[fm][fc][0] * scale;
                float p1 = sacc[fm][fc][1] * scale;
                float p2 = sacc[fm][fc][2] * scale;
                float p3 = sacc[fm][fc][3] * scale;
                if (qt == 0 && w == 0 && fc == 0 && lr == 0) {
                    const int kb = kt * 64 + fm * 16 + lg * 4;
                    p0 += tb[kb + 0]; p1 += tb[kb + 1];
                    p2 += tb[kb + 2]; p3 += tb[kb + 3];
                }
                p0 = __expf(p0) * linv[fc]; p1 = __expf(p1) * linv[fc];
                p2 = __expf(p2) * linv[fc]; p3 = __expf(p3) * linv[fc];
                const int q = qbase + fc * 16 + lr;
                float* dst = W0 + (size_t)(b * LSEQ + q) * LSEQ +
                             kt * 64 + fm * 16 + lg * 4;
                *(float4*)dst = make_float4(p0, p1, p2, p3);
            }
        }
    }
}

// ---------------------------------------------------------------------------
extern "C" void kernel_launch(void* const* d_in, const int* in_sizes, int n_in,
                              void* d_out, int out_size, void* d_ws, size_t ws_size,
                              hipStream_t stream)
{
    const float* s   = (const float*)d_in[0];
    const float* z   = (const float*)d_in[1];
    const float* wq  = (const float*)d_in[2];
    const float* bq  = (const float*)d_in[3];
    const float* wk  = (const float*)d_in[4];
    const float* bk  = (const float*)d_in[5];
    const float* wv  = (const float*)d_in[6];
    const float* bv  = (const float*)d_in[7];
    const float* wo  = (const float*)d_in[8];
    const float* bo  = (const float*)d_in[9];
    const float* wp  = (const float*)d_in[10];
    const float* bp  = (const float*)d_in[11];
    const float* pos = (const float*)d_in[12];
    const float* ew  = (const float*)d_in[13];
    const float* lng = (const float*)d_in[14];
    const float* lnb = (const float*)d_in[15];
    const float* w1  = (const float*)d_in[16];
    const float* b1  = (const float*)d_in[17];
    const float* w2  = (const float*)d_in[18];
    const float* b2  = (const float*)d_in[19];

    float* out = (float*)d_out;
    const size_t oz  = (size_t)NROWS * SDIM;
    const size_t ow  = oz + (size_t)NROWS * 64;
    const size_t ope = ow + (size_t)NROWS * LSEQ;
    const size_t opr = ope + (size_t)NROWS;

    // workspace layout (bytes)
    char* wsb = (char*)d_ws;
    unsigned short* QKV = (unsigned short*)(wsb);             // [32768][1536] bf16, 96MB
    float*          s2f = (float*)(wsb);                      // s2 fp32 64MB (after attn)
    unsigned short* hb  = (unsigned short*)(wsb + 67108864);  // LN2 bf16 32MB (after attn)
    unsigned short* Xb  = (unsigned short*)(wsb + 100663296); // s_ln bf16 -> attn_out bf16
    unsigned short* F   = (unsigned short*)(wsb + 100663296); // FFN mid [32768][2048] bf16 (after WO)
    unsigned short* wqkvt = (unsigned short*)(wsb + 234881024);
    unsigned short* wot = wqkvt + 786432;
    unsigned short* w1t = wqkvt + 1048576;    // [2048][512]
    unsigned short* w2t = wqkvt + 2097152;    // [512][2048]
    unsigned short* wpT = wqkvt + 3145728;    // [32][512]
    float* bqkv = (float*)(wsb + 234881024 + 6324224);
    float* tb   = bqkv + 1536;
    float* lgv  = tb + 512;

    // 0. weight prep
    wtrans<<<dim3(16, 16), 256, 0, stream>>>(wq, wqkvt, 512, 512);
    wtrans<<<dim3(16, 16), 256, 0, stream>>>(wk, wqkvt + 262144, 512, 512);
    wtrans<<<dim3(16, 16), 256, 0, stream>>>(wv, wqkvt + 524288, 512, 512);
    wtrans<<<dim3(16, 16), 256, 0, stream>>>(wo, wot, 512, 512);
    wtrans<<<dim3(64, 16), 256, 0, stream>>>(w1, w1t, 512, 2048);
    wtrans<<<dim3(16, 64), 256, 0, stream>>>(w2, w2t, 2048, 512);
    wptrans<<<64, 256, 0, stream>>>(wp, wpT);
    bpack<<<1, 512, 0, stream>>>(bq, bk, bv, bqkv);

    // 1. LN(s) -> bf16 Xb
    ln_kernel<false><<<NROWS, 256, 0, stream>>>(s, Xb, nullptr, nullptr);

    // 1b. profile softmax + entropy (MFMA)
    profile_kernel<<<256, 256, 0, stream>>>(Xb, wpT, bp, out + opr, out + ope);

    // 2. total bias from batch-0 entropy
    bias_kernel<<<1, 512, 0, stream>>>(out + ope, ew, pos, tb);

    // 3. fused QKV projection -> QKV bf16 [32768][1536]
    mgemm<1, true, false, false><<<dim3(12, 256), 256, 0, stream>>>(
        Xb, 512, wqkvt, 512, QKV, LDQKV, bqkv, nullptr, 0, 512);

    // 4. MFMA attention -> attn_out bf16 (Xb) + rowsums
    attn_mfma<<<dim3(4, NHEAD, BATCH), 256, 0, stream>>>(
        QKV, tb, Xb, lgv);

    // 4b. head-0 normalized attention weights (fp32)
    sw0_kernel<<<dim3(4, BATCH), 256, 0, stream>>>(QKV, tb, lgv, out + ow);

    // 5. s2 = s + attn_out @ wo + bo  (fp32 into s2f)
    mgemm<0, true, false, true><<<dim3(4, 256), 256, 0, stream>>>(
        Xb, 512, wot, 512, s2f, 512, bo, s, 512, 512);

    // 6. h = LN(s2)*g + b -> bf16
    ln_kernel<true><<<NROWS, 256, 0, stream>>>(s2f, hb, lng, lnb);

    // 7. FFN1: F = relu(h @ w1 + b1), bf16 [32768][2048]
    mgemm<1, true, true, false><<<dim3(16, 256), 256, 0, stream>>>(
        hb, 512, w1t, 512, F, 2048, b1, nullptr, 0, 512);

    // 8. FFN2: out0 = F @ w2 + b2 + s2
    mgemm<0, true, false, true><<<dim3(4, 256), 256, 0, stream>>>(
        F, 2048, w2t, 2048, out, 512, b2, s2f, 512, 2048);

    // 9. z passthrough
    hipMemcpyAsync(out + oz, z, (size_t)NROWS * 64 * sizeof(float),
                   hipMemcpyDeviceToDevice, stream);
}